// Round 16
// baseline (78.665 us; speedup 1.0000x reference)
//
#include <hip/hip_runtime.h>
#include <hip/hip_bf16.h>

#define LOG2E 1.4426950408889634f

typedef __attribute__((ext_vector_type(8))) short bf16x8;
typedef __attribute__((ext_vector_type(4))) float f32x4;
typedef __attribute__((ext_vector_type(16))) float f32x16;

__device__ __forceinline__ short f2bf(float a) {
  __hip_bfloat16 h = __float2bfloat16(a);
  return *reinterpret_cast<short*>(&h);
}
__device__ __forceinline__ unsigned pkbf(float a, float b) {
  return (unsigned)(unsigned short)f2bf(a) | ((unsigned)(unsigned short)f2bf(b) << 16);
}
__device__ __forceinline__ unsigned cvtpk(float a, float b) {
  unsigned r;
  asm("v_cvt_pk_bf16_f32 %0, %1, %2" : "=v"(r) : "v"(a), "v"(b));
  return r;
}
__device__ __forceinline__ float bfu2f(unsigned u16v) {
  unsigned v = u16v << 16; float f; __builtin_memcpy(&f, &v, 4); return f;
}
union FragU8 { unsigned d[4]; bf16x8 v; };
union KU { uint4 u; bf16x8 v; };

// ---------------- Kernel P: zero the V-plane halo borders ----------------
__global__ __launch_bounds__(256) void haloattn_prep(
    unsigned short* __restrict__ vpln)
{
  unsigned short* pl = vpln + (size_t)blockIdx.x * 5040;
  for (int e = threadIdx.x; e < 944; e += 256) {
    int off;
    if (e < 216) {
      off = e;                       // rows 0-2
    } else if (e < 432) {
      off = 4824 + (e - 216);        // rows 67-69
    } else {
      const int tt = e - 432;        // 512 middle-border elems
      const int y = 3 + (tt >> 3);
      const int cidx = tt & 7;       // 0,1,2 -> cols 0-2 ; 3..7 -> cols 67-71
      off = y * 72 + (cidx < 3 ? cidx : cidx + 64);
    }
    pl[off] = 0;
  }
}

// ---------------- Kernel 1: fused q/kv projection (bf16 MFMA) ----------------
// cvt FUSED IN: per chk, the X-tile [64k x 128p] is staged from fp32 x with
// coalesced float4 loads and written bf16-transposed into Xt[128][68] (the
// exact LDS layout the round-13 MFMA block consumed). No xT round-trip
// (saves 67 MB HBM + one dispatch); no scalar JIT load chains (rounds 14/15's
// latency trap). W staged fp32->bf16 in-register (proven r14/15).
__global__ __launch_bounds__(512, 2) void haloattn_proj_mfma(
    const float* __restrict__ x, const float* __restrict__ q_w,
    const float* __restrict__ kv_w,
    unsigned short* __restrict__ q_bf, unsigned short* __restrict__ kbuf,
    unsigned short* __restrict__ vpln)
{
  __shared__ unsigned short Wt[256][68];
  __shared__ unsigned short Xt[128][68];
  const int tid = threadIdx.x;
  const int w = tid >> 6, l = tid & 63;
  // swizzle: 512 blocks, 8 XCDs -> XCD i gets swz in [i*64, i*64+64)
  const int wg = blockIdx.x;
  const int swz = ((wg & 7) << 6) | (wg >> 3);
  const int oSel = swz & 1;
  const int px   = (swz >> 1) & 31;
  const int b    = swz >> 6;
  const int oBase = oSel << 8, pBase = px << 7;
  const int wm = w >> 1, wn = w & 1;
  const int g = l >> 4, c = l & 15;

  f32x4 acc[4][4] = {};

  const int srow = tid >> 3;           // 0..63
  const int se3  = (tid & 7) << 3;     // 0..56
  const int kS = tid >> 5;             // 0..15  (X staging)
  const int pS = (tid & 31) << 2;      // 0..124 (X staging)

  const float* xb = x + (size_t)b * (256 * 4096);

  for (int chk = 0; chk < 4; ++chk) {
    const int k0 = chk << 6;
    // ---- stage Wt[256][64] from fp32 weights ----
#pragma unroll
    for (int ps = 0; ps < 4; ++ps) {
      const int row = (ps << 6) + srow;
      const int o = oBase + row;
      const float* wr = (o < 128 ? q_w + (size_t)o * 256
                                 : kv_w + (size_t)(o - 128) * 256) + k0 + se3;
      float4 a = *(const float4*)wr;
      float4 b4 = *(const float4*)(wr + 4);
      char* dst = (char*)&Wt[0][0] + row * 136 + (se3 << 1);
      *(uint2*)dst = make_uint2(cvtpk(a.x, a.y), cvtpk(a.z, a.w));
      *(uint2*)(dst + 8) = make_uint2(cvtpk(b4.x, b4.y), cvtpk(b4.z, b4.w));
    }
    // ---- stage Xt[128][64]: fp32 load (coalesced along p) -> bf16 transpose ----
#pragma unroll
    for (int ks = 0; ks < 4; ++ks) {
      const int kk = (ks << 4) + kS;   // 0..63
      float4 v = *(const float4*)(xb + (size_t)(k0 + kk) * 4096 + pBase + pS);
      Xt[pS + 0][kk] = (unsigned short)f2bf(v.x);
      Xt[pS + 1][kk] = (unsigned short)f2bf(v.y);
      Xt[pS + 2][kk] = (unsigned short)f2bf(v.z);
      Xt[pS + 3][kk] = (unsigned short)f2bf(v.w);
    }
    __syncthreads();
#pragma unroll
    for (int kk = 0; kk < 2; ++kk) {
      FragU8 bfr[4];
#pragma unroll
      for (int nf = 0; nf < 4; ++nf) {
        const char* src = (const char*)&Xt[0][0]
            + ((wn << 6) + (nf << 4) + c) * 136 + (kk << 6) + (g << 4);
        uint2 lo = *(const uint2*)src, hi2 = *(const uint2*)(src + 8);
        bfr[nf].d[0] = lo.x; bfr[nf].d[1] = lo.y;
        bfr[nf].d[2] = hi2.x; bfr[nf].d[3] = hi2.y;
      }
#pragma unroll
      for (int mf = 0; mf < 4; ++mf) {
        const char* src = (const char*)&Wt[0][0]
            + ((wm << 6) + (mf << 4) + c) * 136 + (kk << 6) + (g << 4);
        uint2 lo = *(const uint2*)src, hi2 = *(const uint2*)(src + 8);
        FragU8 af;
        af.d[0] = lo.x; af.d[1] = lo.y; af.d[2] = hi2.x; af.d[3] = hi2.y;
#pragma unroll
        for (int nf = 0; nf < 4; ++nf)
          acc[mf][nf] = __builtin_amdgcn_mfma_f32_16x16x32_bf16(af.v, bfr[nf].v, acc[mf][nf], 0, 0, 0);
      }
    }
    __syncthreads();
  }
#pragma unroll
  for (int mf = 0; mf < 4; ++mf) {
    const int o = oBase + (wm << 6) + (mf << 4) + (g << 2);
#pragma unroll
    for (int nf = 0; nf < 4; ++nf) {
      const int p = pBase + (wn << 6) + (nf << 4) + c;
      if (o < 128) {
        uint2 pk2 = make_uint2(pkbf(acc[mf][nf][0], acc[mf][nf][1]),
                               pkbf(acc[mf][nf][2], acc[mf][nf][3]));
        const int head = o >> 4;
        const int z = (b << 3) + head;
        const int y = p >> 6, xx = p & 63;
        const int nbb = ((y >> 3) << 3) + (xx >> 3);
        const int qi = ((y & 7) << 3) + (xx & 7);
        *(uint2*)(q_bf + (((size_t)z * 64 + nbb) * 64 + qi) * 16 + (o & 15)) = pk2;
      } else {
        const int ch = o - 128;
        const int head = (ch * 1366) >> 16;      // ch/48
        const int wi = ch - head * 48;
        const int b8h = (b << 3) + head;
        if (wi < 16) {
          uint2 pk2 = make_uint2(pkbf(acc[mf][nf][0], acc[mf][nf][1]),
                                 pkbf(acc[mf][nf][2], acc[mf][nf][3]));
          *(uint2*)(kbuf + ((size_t)b8h * 4096 + p) * 16 + wi) = pk2;
        } else {
          const int d = wi - 16;
          const int y = p >> 6, xx = p & 63;
          unsigned short* vp = vpln + (size_t)(b8h * 32 + d) * 5040
                               + (size_t)(y + 3) * 72 + (xx + 3);
          vp[0]     = (unsigned short)f2bf(acc[mf][nf][0]);
          vp[5040]  = (unsigned short)f2bf(acc[mf][nf][1]);
          vp[10080] = (unsigned short)f2bf(acc[mf][nf][2]);
          vp[15120] = (unsigned short)f2bf(acc[mf][nf][3]);
        }
      }
    }
  }
}

// ---------------- Kernel 2: halo attention, 2 waves/tile, XCD-swizzled ----
// (unchanged from round 13)
__global__ __launch_bounds__(128, 2) void haloattn_attn_direct(
    const unsigned short* __restrict__ q_bf, const unsigned short* __restrict__ kbuf,
    const unsigned short* __restrict__ vpln,
    const float* __restrict__ height_rel, const float* __restrict__ width_rel,
    float* __restrict__ out)
{
  __shared__ __align__(16) unsigned short SM[5376];

  const int tid = threadIdx.x;
  const int w = tid >> 6;
  const int l = tid & 63;
  const int q32 = l & 31, hi = l >> 5;
  const int wg = blockIdx.x;
  const int swz = ((wg & 7) << 9) | (wg >> 3);
  const int z = swz >> 6;
  const int nb = swz & 63;
  const int b = z >> 3, head = z & 7;
  const int bi = nb >> 3, bj = nb & 7;
  const int swapA = (l ^ 32) << 2;
  const f32x16 z16 = {};
  const float qs = 0.25f * LOG2E;

  const unsigned short* qtile = q_bf + ((size_t)z * 64 + nb) * 1024;
  bf16x8 qfrag[2];
  qfrag[0] = *(const bf16x8*)(qtile + q32 * 16 + 8 * hi);
  qfrag[1] = *(const bf16x8*)(qtile + (32 + q32) * 16 + 8 * hi);

  unsigned short* HRs = SM;
  unsigned short* WRs = SM + 768;
  if (tid < 54) {
    const int u = tid >> 1, d0 = (tid & 1) << 3;
    float4 a = *(const float4*)(height_rel + u * 16 + d0);
    float4 b4 = *(const float4*)(height_rel + u * 16 + d0 + 4);
    uint4 o;
    o.x = cvtpk(a.x * LOG2E, a.y * LOG2E);
    o.y = cvtpk(a.z * LOG2E, a.w * LOG2E);
    o.z = cvtpk(b4.x * LOG2E, b4.y * LOG2E);
    o.w = cvtpk(b4.z * LOG2E, b4.w * LOG2E);
    *(uint4*)(HRs + u * 24 + d0) = o;
    a = *(const float4*)(width_rel + u * 16 + d0);
    b4 = *(const float4*)(width_rel + u * 16 + d0 + 4);
    o.x = cvtpk(a.x * LOG2E, a.y * LOG2E);
    o.y = cvtpk(a.z * LOG2E, a.w * LOG2E);
    o.z = cvtpk(b4.x * LOG2E, b4.y * LOG2E);
    o.w = cvtpk(b4.z * LOG2E, b4.w * LOG2E);
    *(uint4*)(WRs + u * 24 + d0) = o;
  } else if (tid < 64) {
    const int t = tid - 54;
    const int u = 27 + (t >> 1), d0 = (t & 1) << 3;
    uint4 o = {};
    *(uint4*)(HRs + u * 24 + d0) = o;
    *(uint4*)(WRs + u * 24 + d0) = o;
  }
  __syncthreads();

  {
    bf16x8 hfr = *(const bf16x8*)((const char*)HRs + q32 * 48 + 16 * hi);
    bf16x8 wfr = *(const bf16x8*)((const char*)WRs + q32 * 48 + 16 * hi);
    f32x16 h0 = __builtin_amdgcn_mfma_f32_32x32x16_bf16(hfr, qfrag[0], z16, 0, 0, 0);
    f32x16 h1 = __builtin_amdgcn_mfma_f32_32x32x16_bf16(hfr, qfrag[1], z16, 0, 0, 0);
    f32x16 w0 = __builtin_amdgcn_mfma_f32_32x32x16_bf16(wfr, qfrag[0], z16, 0, 0, 0);
    f32x16 w1 = __builtin_amdgcn_mfma_f32_32x32x16_bf16(wfr, qfrag[1], z16, 0, 0, 0);
    __syncthreads();
    if (w == 0) {
#pragma unroll
      for (int r = 0; r < 16; ++r) {
        const int u = (r & 3) + 8 * (r >> 2) + 4 * hi;
        if (u >= 6 && u < 27) {
          const int rr = u - 6;
          SM[rr * 64 + q32]               = (unsigned short)f2bf(h0[r]);
          SM[(21 + rr) * 64 + q32]        = (unsigned short)f2bf(h1[r]);
          SM[2688 + rr * 64 + q32]        = (unsigned short)f2bf(w0[r]);
          SM[2688 + (21 + rr) * 64 + q32] = (unsigned short)f2bf(w1[r]);
        }
      }
    }
  }
  __syncthreads();

  const int qw = q32 & 7;
  float wreg[2][8];
#pragma unroll
  for (int nt = 0; nt < 2; ++nt)
#pragma unroll
    for (int t = 0; t < 8; ++t) {
      const int jt = (t < 4 ? t : t + 4) + 4 * hi;
      if (jt < 14)
        wreg[nt][t] = bfu2f(SM[2688 + (nt * 21 + 7 - qw + jt) * 64 + q32]);
      else
        wreg[nt][t] = -1e30f;
    }

  const int qh0 = q32 >> 3;
  const unsigned short* Hp0 = SM + (7 - qh0) * 64 + q32;
  const unsigned short* Hp1 = SM + (24 - qh0) * 64 + q32;

  const int jj = q32 & 15, ir = q32 >> 4;
  const int xx = bj * 8 + jj - 3;
  const bool jok = (jj < 14) && ((unsigned)xx < 64u);
  const unsigned short* kb = kbuf + ((size_t)((b << 3) + head) * 4096 + xx) * 16 + 8 * hi;
  const int yy0 = bi * 8 + ir - 3;
  const unsigned short* vb = vpln + (size_t)(((b << 3) + head) * 32 + q32) * 5040
                             + (bi * 8) * 72 + bj * 8 + 8 * hi;

  const int c0w = w ? 4 : 0;
  const int ncw = w ? 3 : 4;

  f32x16 acc[2] = {};
  float lrow[2] = {0.f, 0.f};

  KU k4; k4.u = make_uint4(0, 0, 0, 0);
  {
    const int yy = yy0 + 2 * c0w;
    if (jok && (unsigned)yy < 64u) k4.u = *(const uint4*)(kb + (size_t)yy * 1024);
  }
  bf16x8 v0n = *(const bf16x8*)(vb + (2 * c0w) * 72);
  bf16x8 v1n = *(const bf16x8*)(vb + (2 * c0w + 1) * 72);

  for (int ci = 0; ci < ncw; ++ci) {
    const int c = c0w + ci;
    const bf16x8 kf = k4.v;
    const bf16x8 vf0 = v0n, vf1 = v1n;
    if (ci < ncw - 1) {
      const int yy = yy0 + 2 * (c + 1);
      KU kn; kn.u = make_uint4(0, 0, 0, 0);
      if (jok && (unsigned)yy < 64u) kn.u = *(const uint4*)(kb + (size_t)yy * 1024);
      k4 = kn;
      v0n = *(const bf16x8*)(vb + (2 * c + 2) * 72);
      v1n = *(const bf16x8*)(vb + (2 * c + 3) * 72);
    }
#pragma unroll
    for (int nt = 0; nt < 2; ++nt) {
      f32x16 Cs = __builtin_amdgcn_mfma_f32_32x32x16_bf16(kf, qfrag[nt], z16, 0, 0, 0);
      const unsigned short* Hp = nt ? Hp1 : Hp0;
      const float hA = bfu2f(Hp[(2 * c) * 64]);
      const float hB = bfu2f(Hp[(2 * c + 1) * 64]);
      float p[16];
#pragma unroll
      for (int r = 0; r < 16; ++r) {
        const float wv = wreg[nt][(r & 3) + 4 * ((r >> 2) & 1)];
        const float h = (r < 8) ? hA : hB;
        p[r] = exp2f(fmaf(Cs[r], qs, h + wv));
      }
      {
        float s0 = (p[0] + p[1]) + (p[2] + p[3]);
        float s1 = (p[4] + p[5]) + (p[6] + p[7]);
        float s2 = (p[8] + p[9]) + (p[10] + p[11]);
        float s3 = (p[12] + p[13]) + (p[14] + p[15]);
        lrow[nt] += (s0 + s1) + (s2 + s3);
      }
      unsigned dw[8], xw[8];
#pragma unroll
      for (int k = 0; k < 8; ++k) dw[k] = cvtpk(p[2 * k], p[2 * k + 1]);
#pragma unroll
      for (int k = 0; k < 8; ++k)
        xw[k] = (unsigned)__builtin_amdgcn_ds_bpermute(swapA, (int)dw[k]);
      FragU8 f0, f1;
      f0.d[0] = hi ? xw[2] : dw[0];
      f0.d[1] = hi ? xw[3] : dw[1];
      f0.d[2] = hi ? dw[2] : xw[0];
      f0.d[3] = hi ? dw[3] : xw[1];
      f1.d[0] = hi ? xw[6] : dw[4];
      f1.d[1] = hi ? xw[7] : dw[5];
      f1.d[2] = hi ? dw[6] : xw[4];
      f1.d[3] = hi ? dw[7] : xw[5];
      acc[nt] = __builtin_amdgcn_mfma_f32_32x32x16_bf16(vf0, f0.v, acc[nt], 0, 0, 0);
      acc[nt] = __builtin_amdgcn_mfma_f32_32x32x16_bf16(vf1, f1.v, acc[nt], 0, 0, 0);
    }
  }

  __syncthreads();
  float* F = (float*)SM;
  if (w == 0) {
#pragma unroll
    for (int r = 0; r < 16; ++r) F[l * 17 + r] = acc[1][r];
    F[l * 17 + 16] = lrow[1];
  } else {
#pragma unroll
    for (int r = 0; r < 16; ++r) F[1088 + l * 17 + r] = acc[0][r];
    F[1088 + l * 17 + 16] = lrow[0];
  }
  __syncthreads();
  const int nt = w;
  float am[16];
  float lm;
  if (w == 0) {
#pragma unroll
    for (int r = 0; r < 16; ++r) am[r] = acc[0][r] + F[1088 + l * 17 + r];
    lm = lrow[0] + F[1088 + l * 17 + 16];
  } else {
#pragma unroll
    for (int r = 0; r < 16; ++r) am[r] = acc[1][r] + F[l * 17 + r];
    lm = lrow[1] + F[l * 17 + 16];
  }
  const float L = lm + __shfl_xor(lm, 32);
  const float invL = 1.f / L;
  const int qt = nt * 32 + q32;
  const int yq = bi * 8 + (qt >> 3);
  const int xq = bj * 8 + (q32 & 7);
  float* obase = out + ((size_t)(b * 256 + head * 32) * 4096) + yq * 64 + xq;
#pragma unroll
  for (int r = 0; r < 16; ++r) {
    const int d = (r & 3) + 8 * (r >> 2) + 4 * hi;
    obase[(size_t)d * 4096] = am[r] * invL;
  }
}

extern "C" void kernel_launch(void* const* d_in, const int* in_sizes, int n_in,
                              void* d_out, int out_size, void* d_ws, size_t ws_size,
                              hipStream_t stream) {
  const float* x          = (const float*)d_in[0];
  const float* q_w        = (const float*)d_in[1];
  const float* kv_w       = (const float*)d_in[2];
  const float* height_rel = (const float*)d_in[3];
  const float* width_rel  = (const float*)d_in[4];
  float* out = (float*)d_out;

  unsigned short* q_bf = (unsigned short*)d_ws;            // 4,194,304 u16
  unsigned short* kbuf = q_bf + (size_t)4194304;           // 4,194,304 u16
  unsigned short* vpln = kbuf + (size_t)4194304;           // 10,321,920 u16

  haloattn_prep<<<2048, 256, 0, stream>>>(vpln);
  haloattn_proj_mfma<<<512, 512, 0, stream>>>(x, q_w, kv_w, q_bf, kbuf, vpln);
  haloattn_attn_direct<<<4096, 128, 0, stream>>>(q_bf, kbuf, vpln,
                                                 height_rel, width_rel, out);
}

// Round 17
// 72.363 us; speedup vs baseline: 1.0871x; 1.0871x over previous
//
#include <hip/hip_runtime.h>
#include <hip/hip_bf16.h>

#define LOG2E 1.4426950408889634f

typedef __attribute__((ext_vector_type(8))) short bf16x8;
typedef __attribute__((ext_vector_type(4))) float f32x4;
typedef __attribute__((ext_vector_type(16))) float f32x16;

__device__ __forceinline__ short f2bf(float a) {
  __hip_bfloat16 h = __float2bfloat16(a);
  return *reinterpret_cast<short*>(&h);
}
__device__ __forceinline__ unsigned pkbf(float a, float b) {
  return (unsigned)(unsigned short)f2bf(a) | ((unsigned)(unsigned short)f2bf(b) << 16);
}
__device__ __forceinline__ unsigned cvtpk(float a, float b) {
  unsigned r;
  asm("v_cvt_pk_bf16_f32 %0, %1, %2" : "=v"(r) : "v"(a), "v"(b));
  return r;
}
__device__ __forceinline__ float bfu2f(unsigned u16v) {
  unsigned v = u16v << 16; float f; __builtin_memcpy(&f, &v, 4); return f;
}
union FragU8 { unsigned d[4]; bf16x8 v; };
union KU { uint4 u; bf16x8 v; };

// ---------------- Kernel 0: transpose-convert + W convert + V-border zero ----
__global__ __launch_bounds__(256) void haloattn_cvt(
    const float* __restrict__ x, const float* __restrict__ q_w,
    const float* __restrict__ kv_w, unsigned short* __restrict__ xT,
    unsigned short* __restrict__ w_bf, unsigned short* __restrict__ vpln)
{
  __shared__ float Ld[64][68];
  const int t = threadIdx.x;
  const int pt = blockIdx.x, kt = blockIdx.y, b = blockIdx.z;
  const int flat = ((b << 2) + kt) * 64 + pt;   // 0..2047, unique per block
  // W convert side-job
  {
    const int idx = flat * 64 + (t & 63);
    if (t < 64) {
      const float wv = (idx < 32768) ? q_w[idx] : kv_w[idx - 32768];
      w_bf[idx] = (unsigned short)f2bf(wv);
    }
  }
  // V-plane halo border zero side-job (plane 'flat'; interior rewritten by proj)
  {
    unsigned short* pl = vpln + (size_t)flat * 5040;
    for (int e = t; e < 944; e += 256) {
      int off;
      if (e < 216) {
        off = e;                       // rows 0-2
      } else if (e < 432) {
        off = 4824 + (e - 216);        // rows 67-69
      } else {
        const int tt = e - 432;        // 512 middle-border elems
        const int y = 3 + (tt >> 3);
        const int cidx = tt & 7;       // 0,1,2 -> cols 0-2 ; 3..7 -> cols 67-71
        off = y * 72 + (cidx < 3 ? cidx : cidx + 64);
      }
      pl[off] = 0;
    }
  }
  const float* xb = x + ((size_t)b * 256 + (kt << 6)) * 4096 + (pt << 6);
#pragma unroll
  for (int ps = 0; ps < 4; ++ps) {
    const int kloc = (ps << 4) + (t >> 4);
    const int ploc = (t & 15) << 2;
    float4 v = *(const float4*)(xb + (size_t)kloc * 4096 + ploc);
    *(float4*)&Ld[kloc][ploc] = v;
  }
  __syncthreads();
  const int pl = t >> 2;
  const int ks = (t & 3) << 4;
  float f[16];
#pragma unroll
  for (int i = 0; i < 16; ++i) f[i] = Ld[ks + i][pl];
  uint4 o0, o1;
  o0.x = pkbf(f[0], f[1]);   o0.y = pkbf(f[2], f[3]);
  o0.z = pkbf(f[4], f[5]);   o0.w = pkbf(f[6], f[7]);
  o1.x = pkbf(f[8], f[9]);   o1.y = pkbf(f[10], f[11]);
  o1.z = pkbf(f[12], f[13]); o1.w = pkbf(f[14], f[15]);
  unsigned short* op = xT + ((size_t)(b << 12) + (pt << 6) + pl) * 256 + (kt << 6) + ks;
  *(uint4*)op = o0;
  *(uint4*)(op + 8) = o1;
}

// ---------------- Kernel 1: fused q/kv projection (bf16 MFMA) ----------------
__global__ __launch_bounds__(512, 4) void haloattn_proj_mfma(
    const unsigned short* __restrict__ xT, const unsigned short* __restrict__ w_bf,
    unsigned short* __restrict__ q_bf, unsigned short* __restrict__ kbuf,
    unsigned short* __restrict__ vpln)
{
  __shared__ unsigned short Wt[256][68];
  __shared__ unsigned short Xt[128][68];
  const int tid = threadIdx.x;
  const int w = tid >> 6, l = tid & 63;
  const int b = blockIdx.z, oBase = blockIdx.y << 8, pBase = blockIdx.x << 7;
  const int wm = w >> 1, wn = w & 1;
  const int g = l >> 4, c = l & 15;

  f32x4 acc[4][4] = {};

  const int srow = tid >> 3;
  const int se3  = (tid & 7) << 3;

  for (int chk = 0; chk < 4; ++chk) {
    const int k0 = chk << 6;
#pragma unroll
    for (int ps = 0; ps < 4; ++ps) {
      const int row = (ps << 6) + srow;
      uint4 wv = *(const uint4*)(w_bf + (size_t)(oBase + row) * 256 + k0 + se3);
      char* dst = (char*)&Wt[0][0] + row * 136 + (se3 << 1);
      *(uint2*)dst = make_uint2(wv.x, wv.y);
      *(uint2*)(dst + 8) = make_uint2(wv.z, wv.w);
    }
#pragma unroll
    for (int ps = 0; ps < 2; ++ps) {
      const int p = (ps << 6) + srow;
      uint4 xv = *(const uint4*)(xT + ((size_t)(b << 12) + pBase + p) * 256 + k0 + se3);
      char* dst = (char*)&Xt[0][0] + p * 136 + (se3 << 1);
      *(uint2*)dst = make_uint2(xv.x, xv.y);
      *(uint2*)(dst + 8) = make_uint2(xv.z, xv.w);
    }
    __syncthreads();
#pragma unroll
    for (int kk = 0; kk < 2; ++kk) {
      FragU8 bfr[4];
#pragma unroll
      for (int nf = 0; nf < 4; ++nf) {
        const char* src = (const char*)&Xt[0][0]
            + ((wn << 6) + (nf << 4) + c) * 136 + (kk << 6) + (g << 4);
        uint2 lo = *(const uint2*)src, hi2 = *(const uint2*)(src + 8);
        bfr[nf].d[0] = lo.x; bfr[nf].d[1] = lo.y;
        bfr[nf].d[2] = hi2.x; bfr[nf].d[3] = hi2.y;
      }
#pragma unroll
      for (int mf = 0; mf < 4; ++mf) {
        const char* src = (const char*)&Wt[0][0]
            + ((wm << 6) + (mf << 4) + c) * 136 + (kk << 6) + (g << 4);
        uint2 lo = *(const uint2*)src, hi2 = *(const uint2*)(src + 8);
        FragU8 af;
        af.d[0] = lo.x; af.d[1] = lo.y; af.d[2] = hi2.x; af.d[3] = hi2.y;
#pragma unroll
        for (int nf = 0; nf < 4; ++nf)
          acc[mf][nf] = __builtin_amdgcn_mfma_f32_16x16x32_bf16(af.v, bfr[nf].v, acc[mf][nf], 0, 0, 0);
      }
    }
    __syncthreads();
  }
#pragma unroll
  for (int mf = 0; mf < 4; ++mf) {
    const int o = oBase + (wm << 6) + (mf << 4) + (g << 2);
#pragma unroll
    for (int nf = 0; nf < 4; ++nf) {
      const int p = pBase + (wn << 6) + (nf << 4) + c;
      if (o < 128) {
        uint2 pk2 = make_uint2(pkbf(acc[mf][nf][0], acc[mf][nf][1]),
                               pkbf(acc[mf][nf][2], acc[mf][nf][3]));
        const int head = o >> 4;
        const int z = (b << 3) + head;
        const int y = p >> 6, xx = p & 63;
        const int nbb = ((y >> 3) << 3) + (xx >> 3);
        const int qi = ((y & 7) << 3) + (xx & 7);
        *(uint2*)(q_bf + (((size_t)z * 64 + nbb) * 64 + qi) * 16 + (o & 15)) = pk2;
      } else {
        const int ch = o - 128;
        const int head = (ch * 1366) >> 16;      // ch/48
        const int wi = ch - head * 48;
        const int b8h = (b << 3) + head;
        if (wi < 16) {
          uint2 pk2 = make_uint2(pkbf(acc[mf][nf][0], acc[mf][nf][1]),
                                 pkbf(acc[mf][nf][2], acc[mf][nf][3]));
          *(uint2*)(kbuf + ((size_t)b8h * 4096 + p) * 16 + wi) = pk2;
        } else {
          const int d = wi - 16;
          const int y = p >> 6, xx = p & 63;
          unsigned short* vp = vpln + (size_t)(b8h * 32 + d) * 5040
                               + (size_t)(y + 3) * 72 + (xx + 3);
          vp[0]     = (unsigned short)f2bf(acc[mf][nf][0]);
          vp[5040]  = (unsigned short)f2bf(acc[mf][nf][1]);
          vp[10080] = (unsigned short)f2bf(acc[mf][nf][2]);
          vp[15120] = (unsigned short)f2bf(acc[mf][nf][3]);
        }
      }
    }
  }
}

// ---------------- Kernel 2: halo attention, 2 waves/tile, XCD-swizzled ----
// r13 base + T5: s_setprio(1) around MFMA clusters (waves independent in the
// main loop -> scheduler role diversity; measured +4-7% on attn-like kernels).
__global__ __launch_bounds__(128, 2) void haloattn_attn_direct(
    const unsigned short* __restrict__ q_bf, const unsigned short* __restrict__ kbuf,
    const unsigned short* __restrict__ vpln,
    const float* __restrict__ height_rel, const float* __restrict__ width_rel,
    float* __restrict__ out)
{
  __shared__ __align__(16) unsigned short SM[5376];

  const int tid = threadIdx.x;
  const int w = tid >> 6;
  const int l = tid & 63;
  const int q32 = l & 31, hi = l >> 5;
  const int wg = blockIdx.x;
  const int swz = ((wg & 7) << 9) | (wg >> 3);
  const int z = swz >> 6;
  const int nb = swz & 63;
  const int b = z >> 3, head = z & 7;
  const int bi = nb >> 3, bj = nb & 7;
  const int swapA = (l ^ 32) << 2;
  const f32x16 z16 = {};
  const float qs = 0.25f * LOG2E;

  const unsigned short* qtile = q_bf + ((size_t)z * 64 + nb) * 1024;
  bf16x8 qfrag[2];
  qfrag[0] = *(const bf16x8*)(qtile + q32 * 16 + 8 * hi);
  qfrag[1] = *(const bf16x8*)(qtile + (32 + q32) * 16 + 8 * hi);

  unsigned short* HRs = SM;
  unsigned short* WRs = SM + 768;
  if (tid < 54) {
    const int u = tid >> 1, d0 = (tid & 1) << 3;
    float4 a = *(const float4*)(height_rel + u * 16 + d0);
    float4 b4 = *(const float4*)(height_rel + u * 16 + d0 + 4);
    uint4 o;
    o.x = cvtpk(a.x * LOG2E, a.y * LOG2E);
    o.y = cvtpk(a.z * LOG2E, a.w * LOG2E);
    o.z = cvtpk(b4.x * LOG2E, b4.y * LOG2E);
    o.w = cvtpk(b4.z * LOG2E, b4.w * LOG2E);
    *(uint4*)(HRs + u * 24 + d0) = o;
    a = *(const float4*)(width_rel + u * 16 + d0);
    b4 = *(const float4*)(width_rel + u * 16 + d0 + 4);
    o.x = cvtpk(a.x * LOG2E, a.y * LOG2E);
    o.y = cvtpk(a.z * LOG2E, a.w * LOG2E);
    o.z = cvtpk(b4.x * LOG2E, b4.y * LOG2E);
    o.w = cvtpk(b4.z * LOG2E, b4.w * LOG2E);
    *(uint4*)(WRs + u * 24 + d0) = o;
  } else if (tid < 64) {
    const int t = tid - 54;
    const int u = 27 + (t >> 1), d0 = (t & 1) << 3;
    uint4 o = {};
    *(uint4*)(HRs + u * 24 + d0) = o;
    *(uint4*)(WRs + u * 24 + d0) = o;
  }
  __syncthreads();

  {
    bf16x8 hfr = *(const bf16x8*)((const char*)HRs + q32 * 48 + 16 * hi);
    bf16x8 wfr = *(const bf16x8*)((const char*)WRs + q32 * 48 + 16 * hi);
    f32x16 h0 = __builtin_amdgcn_mfma_f32_32x32x16_bf16(hfr, qfrag[0], z16, 0, 0, 0);
    f32x16 h1 = __builtin_amdgcn_mfma_f32_32x32x16_bf16(hfr, qfrag[1], z16, 0, 0, 0);
    f32x16 w0 = __builtin_amdgcn_mfma_f32_32x32x16_bf16(wfr, qfrag[0], z16, 0, 0, 0);
    f32x16 w1 = __builtin_amdgcn_mfma_f32_32x32x16_bf16(wfr, qfrag[1], z16, 0, 0, 0);
    __syncthreads();
    if (w == 0) {
#pragma unroll
      for (int r = 0; r < 16; ++r) {
        const int u = (r & 3) + 8 * (r >> 2) + 4 * hi;
        if (u >= 6 && u < 27) {
          const int rr = u - 6;
          SM[rr * 64 + q32]               = (unsigned short)f2bf(h0[r]);
          SM[(21 + rr) * 64 + q32]        = (unsigned short)f2bf(h1[r]);
          SM[2688 + rr * 64 + q32]        = (unsigned short)f2bf(w0[r]);
          SM[2688 + (21 + rr) * 64 + q32] = (unsigned short)f2bf(w1[r]);
        }
      }
    }
  }
  __syncthreads();

  const int qw = q32 & 7;
  float wreg[2][8];
#pragma unroll
  for (int nt = 0; nt < 2; ++nt)
#pragma unroll
    for (int t = 0; t < 8; ++t) {
      const int jt = (t < 4 ? t : t + 4) + 4 * hi;
      if (jt < 14)
        wreg[nt][t] = bfu2f(SM[2688 + (nt * 21 + 7 - qw + jt) * 64 + q32]);
      else
        wreg[nt][t] = -1e30f;
    }

  const int qh0 = q32 >> 3;
  const unsigned short* Hp0 = SM + (7 - qh0) * 64 + q32;
  const unsigned short* Hp1 = SM + (24 - qh0) * 64 + q32;

  const int jj = q32 & 15, ir = q32 >> 4;
  const int xx = bj * 8 + jj - 3;
  const bool jok = (jj < 14) && ((unsigned)xx < 64u);
  const unsigned short* kb = kbuf + ((size_t)((b << 3) + head) * 4096 + xx) * 16 + 8 * hi;
  const int yy0 = bi * 8 + ir - 3;
  const unsigned short* vb = vpln + (size_t)(((b << 3) + head) * 32 + q32) * 5040
                             + (bi * 8) * 72 + bj * 8 + 8 * hi;

  const int c0w = w ? 4 : 0;
  const int ncw = w ? 3 : 4;

  f32x16 acc[2] = {};
  float lrow[2] = {0.f, 0.f};

  KU k4; k4.u = make_uint4(0, 0, 0, 0);
  {
    const int yy = yy0 + 2 * c0w;
    if (jok && (unsigned)yy < 64u) k4.u = *(const uint4*)(kb + (size_t)yy * 1024);
  }
  bf16x8 v0n = *(const bf16x8*)(vb + (2 * c0w) * 72);
  bf16x8 v1n = *(const bf16x8*)(vb + (2 * c0w + 1) * 72);

  for (int ci = 0; ci < ncw; ++ci) {
    const int c = c0w + ci;
    const bf16x8 kf = k4.v;
    const bf16x8 vf0 = v0n, vf1 = v1n;
    if (ci < ncw - 1) {
      const int yy = yy0 + 2 * (c + 1);
      KU kn; kn.u = make_uint4(0, 0, 0, 0);
      if (jok && (unsigned)yy < 64u) kn.u = *(const uint4*)(kb + (size_t)yy * 1024);
      k4 = kn;
      v0n = *(const bf16x8*)(vb + (2 * c + 2) * 72);
      v1n = *(const bf16x8*)(vb + (2 * c + 3) * 72);
    }
#pragma unroll
    for (int nt = 0; nt < 2; ++nt) {
      __builtin_amdgcn_s_setprio(1);
      f32x16 Cs = __builtin_amdgcn_mfma_f32_32x32x16_bf16(kf, qfrag[nt], z16, 0, 0, 0);
      __builtin_amdgcn_s_setprio(0);
      const unsigned short* Hp = nt ? Hp1 : Hp0;
      const float hA = bfu2f(Hp[(2 * c) * 64]);
      const float hB = bfu2f(Hp[(2 * c + 1) * 64]);
      float p[16];
#pragma unroll
      for (int r = 0; r < 16; ++r) {
        const float wv = wreg[nt][(r & 3) + 4 * ((r >> 2) & 1)];
        const float h = (r < 8) ? hA : hB;
        p[r] = exp2f(fmaf(Cs[r], qs, h + wv));
      }
      {
        float s0 = (p[0] + p[1]) + (p[2] + p[3]);
        float s1 = (p[4] + p[5]) + (p[6] + p[7]);
        float s2 = (p[8] + p[9]) + (p[10] + p[11]);
        float s3 = (p[12] + p[13]) + (p[14] + p[15]);
        lrow[nt] += (s0 + s1) + (s2 + s3);
      }
      unsigned dw[8], xw[8];
#pragma unroll
      for (int k = 0; k < 8; ++k) dw[k] = cvtpk(p[2 * k], p[2 * k + 1]);
#pragma unroll
      for (int k = 0; k < 8; ++k)
        xw[k] = (unsigned)__builtin_amdgcn_ds_bpermute(swapA, (int)dw[k]);
      FragU8 f0, f1;
      f0.d[0] = hi ? xw[2] : dw[0];
      f0.d[1] = hi ? xw[3] : dw[1];
      f0.d[2] = hi ? dw[2] : xw[0];
      f0.d[3] = hi ? dw[3] : xw[1];
      f1.d[0] = hi ? xw[6] : dw[4];
      f1.d[1] = hi ? xw[7] : dw[5];
      f1.d[2] = hi ? dw[6] : xw[4];
      f1.d[3] = hi ? dw[7] : xw[5];
      __builtin_amdgcn_s_setprio(1);
      acc[nt] = __builtin_amdgcn_mfma_f32_32x32x16_bf16(vf0, f0.v, acc[nt], 0, 0, 0);
      acc[nt] = __builtin_amdgcn_mfma_f32_32x32x16_bf16(vf1, f1.v, acc[nt], 0, 0, 0);
      __builtin_amdgcn_s_setprio(0);
    }
  }

  __syncthreads();
  float* F = (float*)SM;
  if (w == 0) {
#pragma unroll
    for (int r = 0; r < 16; ++r) F[l * 17 + r] = acc[1][r];
    F[l * 17 + 16] = lrow[1];
  } else {
#pragma unroll
    for (int r = 0; r < 16; ++r) F[1088 + l * 17 + r] = acc[0][r];
    F[1088 + l * 17 + 16] = lrow[0];
  }
  __syncthreads();
  const int nt = w;
  float am[16];
  float lm;
  if (w == 0) {
#pragma unroll
    for (int r = 0; r < 16; ++r) am[r] = acc[0][r] + F[1088 + l * 17 + r];
    lm = lrow[0] + F[1088 + l * 17 + 16];
  } else {
#pragma unroll
    for (int r = 0; r < 16; ++r) am[r] = acc[1][r] + F[l * 17 + r];
    lm = lrow[1] + F[l * 17 + 16];
  }
  const float L = lm + __shfl_xor(lm, 32);
  const float invL = 1.f / L;
  const int qt = nt * 32 + q32;
  const int yq = bi * 8 + (qt >> 3);
  const int xq = bj * 8 + (q32 & 7);
  float* obase = out + ((size_t)(b * 256 + head * 32) * 4096) + yq * 64 + xq;
#pragma unroll
  for (int r = 0; r < 16; ++r) {
    const int d = (r & 3) + 8 * (r >> 2) + 4 * hi;
    obase[(size_t)d * 4096] = am[r] * invL;
  }
}

extern "C" void kernel_launch(void* const* d_in, const int* in_sizes, int n_in,
                              void* d_out, int out_size, void* d_ws, size_t ws_size,
                              hipStream_t stream) {
  const float* x          = (const float*)d_in[0];
  const float* q_w        = (const float*)d_in[1];
  const float* kv_w       = (const float*)d_in[2];
  const float* height_rel = (const float*)d_in[3];
  const float* width_rel  = (const float*)d_in[4];
  float* out = (float*)d_out;

  unsigned short* q_bf = (unsigned short*)d_ws;            // 4,194,304 u16
  unsigned short* xT   = q_bf + (size_t)4194304;           // 8,388,608 u16
  unsigned short* w_bf = xT + (size_t)8388608;             //   131,072 u16
  unsigned short* kbuf = w_bf + (size_t)131072;            // 4,194,304 u16
  unsigned short* vpln = kbuf + (size_t)4194304;           // 10,321,920 u16

  haloattn_cvt<<<dim3(64, 4, 8), 256, 0, stream>>>(x, q_w, kv_w, xT, w_bf, vpln);
  haloattn_proj_mfma<<<dim3(32, 2, 8), 512, 0, stream>>>(xT, w_bf, q_bf, kbuf, vpln);
  haloattn_attn_direct<<<4096, 128, 0, stream>>>(q_bf, kbuf, vpln,
                                                 height_rel, width_rel, out);
}

// Round 18
// 66.291 us; speedup vs baseline: 1.1867x; 1.0916x over previous
//
#include <hip/hip_runtime.h>
#include <hip/hip_bf16.h>

#define LOG2E 1.4426950408889634f

typedef __attribute__((ext_vector_type(8))) short bf16x8;
typedef __attribute__((ext_vector_type(4))) float f32x4;
typedef __attribute__((ext_vector_type(16))) float f32x16;

__device__ __forceinline__ short f2bf(float a) {
  __hip_bfloat16 h = __float2bfloat16(a);
  return *reinterpret_cast<short*>(&h);
}
__device__ __forceinline__ unsigned pkbf(float a, float b) {
  return (unsigned)(unsigned short)f2bf(a) | ((unsigned)(unsigned short)f2bf(b) << 16);
}
__device__ __forceinline__ unsigned cvtpk(float a, float b) {
  unsigned r;
  asm("v_cvt_pk_bf16_f32 %0, %1, %2" : "=v"(r) : "v"(a), "v"(b));
  return r;
}
__device__ __forceinline__ float bfu2f(unsigned u16v) {
  unsigned v = u16v << 16; float f; __builtin_memcpy(&f, &v, 4); return f;
}
union FragU8 { unsigned d[4]; bf16x8 v; };
union KU { uint4 u; bf16x8 v; };

// ---------------- Kernel 0: transpose-convert + W convert + V-border zero ----
__global__ __launch_bounds__(256) void haloattn_cvt(
    const float* __restrict__ x, const float* __restrict__ q_w,
    const float* __restrict__ kv_w, unsigned short* __restrict__ xT,
    unsigned short* __restrict__ w_bf, unsigned short* __restrict__ vpln)
{
  __shared__ float Ld[64][68];
  const int t = threadIdx.x;
  const int pt = blockIdx.x, kt = blockIdx.y, b = blockIdx.z;
  const int flat = ((b << 2) + kt) * 64 + pt;   // 0..2047, unique per block
  // W convert side-job
  {
    const int idx = flat * 64 + (t & 63);
    if (t < 64) {
      const float wv = (idx < 32768) ? q_w[idx] : kv_w[idx - 32768];
      w_bf[idx] = (unsigned short)f2bf(wv);
    }
  }
  // V-plane halo border zero side-job (plane 'flat'; interior rewritten by proj)
  {
    unsigned short* pl = vpln + (size_t)flat * 5040;
    for (int e = t; e < 944; e += 256) {
      int off;
      if (e < 216) {
        off = e;                       // rows 0-2
      } else if (e < 432) {
        off = 4824 + (e - 216);        // rows 67-69
      } else {
        const int tt = e - 432;        // 512 middle-border elems
        const int y = 3 + (tt >> 3);
        const int cidx = tt & 7;       // 0,1,2 -> cols 0-2 ; 3..7 -> cols 67-71
        off = y * 72 + (cidx < 3 ? cidx : cidx + 64);
      }
      pl[off] = 0;
    }
  }
  const float* xb = x + ((size_t)b * 256 + (kt << 6)) * 4096 + (pt << 6);
#pragma unroll
  for (int ps = 0; ps < 4; ++ps) {
    const int kloc = (ps << 4) + (t >> 4);
    const int ploc = (t & 15) << 2;
    float4 v = *(const float4*)(xb + (size_t)kloc * 4096 + ploc);
    *(float4*)&Ld[kloc][ploc] = v;
  }
  __syncthreads();
  const int pl = t >> 2;
  const int ks = (t & 3) << 4;
  float f[16];
#pragma unroll
  for (int i = 0; i < 16; ++i) f[i] = Ld[ks + i][pl];
  uint4 o0, o1;
  o0.x = pkbf(f[0], f[1]);   o0.y = pkbf(f[2], f[3]);
  o0.z = pkbf(f[4], f[5]);   o0.w = pkbf(f[6], f[7]);
  o1.x = pkbf(f[8], f[9]);   o1.y = pkbf(f[10], f[11]);
  o1.z = pkbf(f[12], f[13]); o1.w = pkbf(f[14], f[15]);
  unsigned short* op = xT + ((size_t)(b << 12) + (pt << 6) + pl) * 256 + (kt << 6) + ks;
  *(uint4*)op = o0;
  *(uint4*)(op + 8) = o1;
}

// ---------------- Kernel 1: fused q/kv projection (bf16 MFMA) ----------------
__global__ __launch_bounds__(512, 4) void haloattn_proj_mfma(
    const unsigned short* __restrict__ xT, const unsigned short* __restrict__ w_bf,
    unsigned short* __restrict__ q_bf, unsigned short* __restrict__ kbuf,
    unsigned short* __restrict__ vpln)
{
  __shared__ unsigned short Wt[256][68];
  __shared__ unsigned short Xt[128][68];
  const int tid = threadIdx.x;
  const int w = tid >> 6, l = tid & 63;
  const int b = blockIdx.z, oBase = blockIdx.y << 8, pBase = blockIdx.x << 7;
  const int wm = w >> 1, wn = w & 1;
  const int g = l >> 4, c = l & 15;

  f32x4 acc[4][4] = {};

  const int srow = tid >> 3;
  const int se3  = (tid & 7) << 3;

  for (int chk = 0; chk < 4; ++chk) {
    const int k0 = chk << 6;
#pragma unroll
    for (int ps = 0; ps < 4; ++ps) {
      const int row = (ps << 6) + srow;
      uint4 wv = *(const uint4*)(w_bf + (size_t)(oBase + row) * 256 + k0 + se3);
      char* dst = (char*)&Wt[0][0] + row * 136 + (se3 << 1);
      *(uint2*)dst = make_uint2(wv.x, wv.y);
      *(uint2*)(dst + 8) = make_uint2(wv.z, wv.w);
    }
#pragma unroll
    for (int ps = 0; ps < 2; ++ps) {
      const int p = (ps << 6) + srow;
      uint4 xv = *(const uint4*)(xT + ((size_t)(b << 12) + pBase + p) * 256 + k0 + se3);
      char* dst = (char*)&Xt[0][0] + p * 136 + (se3 << 1);
      *(uint2*)dst = make_uint2(xv.x, xv.y);
      *(uint2*)(dst + 8) = make_uint2(xv.z, xv.w);
    }
    __syncthreads();
#pragma unroll
    for (int kk = 0; kk < 2; ++kk) {
      FragU8 bfr[4];
#pragma unroll
      for (int nf = 0; nf < 4; ++nf) {
        const char* src = (const char*)&Xt[0][0]
            + ((wn << 6) + (nf << 4) + c) * 136 + (kk << 6) + (g << 4);
        uint2 lo = *(const uint2*)src, hi2 = *(const uint2*)(src + 8);
        bfr[nf].d[0] = lo.x; bfr[nf].d[1] = lo.y;
        bfr[nf].d[2] = hi2.x; bfr[nf].d[3] = hi2.y;
      }
#pragma unroll
      for (int mf = 0; mf < 4; ++mf) {
        const char* src = (const char*)&Wt[0][0]
            + ((wm << 6) + (mf << 4) + c) * 136 + (kk << 6) + (g << 4);
        uint2 lo = *(const uint2*)src, hi2 = *(const uint2*)(src + 8);
        FragU8 af;
        af.d[0] = lo.x; af.d[1] = lo.y; af.d[2] = hi2.x; af.d[3] = hi2.y;
#pragma unroll
        for (int nf = 0; nf < 4; ++nf)
          acc[mf][nf] = __builtin_amdgcn_mfma_f32_16x16x32_bf16(af.v, bfr[nf].v, acc[mf][nf], 0, 0, 0);
      }
    }
    __syncthreads();
  }
#pragma unroll
  for (int mf = 0; mf < 4; ++mf) {
    const int o = oBase + (wm << 6) + (mf << 4) + (g << 2);
#pragma unroll
    for (int nf = 0; nf < 4; ++nf) {
      const int p = pBase + (wn << 6) + (nf << 4) + c;
      if (o < 128) {
        uint2 pk2 = make_uint2(pkbf(acc[mf][nf][0], acc[mf][nf][1]),
                               pkbf(acc[mf][nf][2], acc[mf][nf][3]));
        const int head = o >> 4;
        const int z = (b << 3) + head;
        const int y = p >> 6, xx = p & 63;
        const int nbb = ((y >> 3) << 3) + (xx >> 3);
        const int qi = ((y & 7) << 3) + (xx & 7);
        *(uint2*)(q_bf + (((size_t)z * 64 + nbb) * 64 + qi) * 16 + (o & 15)) = pk2;
      } else {
        const int ch = o - 128;
        const int head = (ch * 1366) >> 16;      // ch/48
        const int wi = ch - head * 48;
        const int b8h = (b << 3) + head;
        if (wi < 16) {
          uint2 pk2 = make_uint2(pkbf(acc[mf][nf][0], acc[mf][nf][1]),
                                 pkbf(acc[mf][nf][2], acc[mf][nf][3]));
          *(uint2*)(kbuf + ((size_t)b8h * 4096 + p) * 16 + wi) = pk2;
        } else {
          const int d = wi - 16;
          const int y = p >> 6, xx = p & 63;
          unsigned short* vp = vpln + (size_t)(b8h * 32 + d) * 5040
                               + (size_t)(y + 3) * 72 + (xx + 3);
          vp[0]     = (unsigned short)f2bf(acc[mf][nf][0]);
          vp[5040]  = (unsigned short)f2bf(acc[mf][nf][1]);
          vp[10080] = (unsigned short)f2bf(acc[mf][nf][2]);
          vp[15120] = (unsigned short)f2bf(acc[mf][nf][3]);
        }
      }
    }
  }
}

// ---------------- Kernel 2: halo attention, waves split by q-half (nt=w) ----
// Each wave owns q-rows [32w,32w+32) over ALL 7 chunks: acc 32->16 regs,
// wreg 16->8, qfrag 16->8, NO cross-wave merge (waves independent after
// prologue). K/V loads duplicated across waves but L1-hit (same CU).
// Target: VGPR <=128 -> 4 waves/SIMD (occupancy was the r13 limiter at ~33%).
__global__ __launch_bounds__(128, 2) void haloattn_attn_direct(
    const unsigned short* __restrict__ q_bf, const unsigned short* __restrict__ kbuf,
    const unsigned short* __restrict__ vpln,
    const float* __restrict__ height_rel, const float* __restrict__ width_rel,
    float* __restrict__ out)
{
  __shared__ __align__(16) unsigned short SM[5376];

  const int tid = threadIdx.x;
  const int w = tid >> 6;          // wave id = nt half
  const int l = tid & 63;
  const int q32 = l & 31, hi = l >> 5;
  const int wg = blockIdx.x;
  const int swz = ((wg & 7) << 9) | (wg >> 3);
  const int z = swz >> 6;
  const int nb = swz & 63;
  const int b = z >> 3, head = z & 7;
  const int bi = nb >> 3, bj = nb & 7;
  const int swapA = (l ^ 32) << 2;
  const f32x16 z16 = {};
  const float qs = 0.25f * LOG2E;

  // ---- Q fragment for this wave's q-half ----
  const unsigned short* qtile = q_bf + ((size_t)z * 64 + nb) * 1024;
  const bf16x8 qfrag = *(const bf16x8*)(qtile + (((w << 5) + q32) << 4) + 8 * hi);

  // ---- stage rel tables (bf16 * LOG2E) ----
  unsigned short* HRs = SM;
  unsigned short* WRs = SM + 768;
  if (tid < 54) {
    const int u = tid >> 1, d0 = (tid & 1) << 3;
    float4 a = *(const float4*)(height_rel + u * 16 + d0);
    float4 b4 = *(const float4*)(height_rel + u * 16 + d0 + 4);
    uint4 o;
    o.x = cvtpk(a.x * LOG2E, a.y * LOG2E);
    o.y = cvtpk(a.z * LOG2E, a.w * LOG2E);
    o.z = cvtpk(b4.x * LOG2E, b4.y * LOG2E);
    o.w = cvtpk(b4.z * LOG2E, b4.w * LOG2E);
    *(uint4*)(HRs + u * 24 + d0) = o;
    a = *(const float4*)(width_rel + u * 16 + d0);
    b4 = *(const float4*)(width_rel + u * 16 + d0 + 4);
    o.x = cvtpk(a.x * LOG2E, a.y * LOG2E);
    o.y = cvtpk(a.z * LOG2E, a.w * LOG2E);
    o.z = cvtpk(b4.x * LOG2E, b4.y * LOG2E);
    o.w = cvtpk(b4.z * LOG2E, b4.w * LOG2E);
    *(uint4*)(WRs + u * 24 + d0) = o;
  } else if (tid < 64) {
    const int t = tid - 54;
    const int u = 27 + (t >> 1), d0 = (t & 1) << 3;
    uint4 o = {};
    *(uint4*)(HRs + u * 24 + d0) = o;
    *(uint4*)(WRs + u * 24 + d0) = o;
  }
  __syncthreads();

  // ---- pos-embed tables via MFMA: each wave builds its own nt=w half ----
  {
    bf16x8 hfr = *(const bf16x8*)((const char*)HRs + q32 * 48 + 16 * hi);
    bf16x8 wfr = *(const bf16x8*)((const char*)WRs + q32 * 48 + 16 * hi);
    f32x16 hC = __builtin_amdgcn_mfma_f32_32x32x16_bf16(hfr, qfrag, z16, 0, 0, 0);
    f32x16 wC = __builtin_amdgcn_mfma_f32_32x32x16_bf16(wfr, qfrag, z16, 0, 0, 0);
    __syncthreads();   // staging reads complete before overwrite
#pragma unroll
    for (int r = 0; r < 16; ++r) {
      const int u = (r & 3) + 8 * (r >> 2) + 4 * hi;
      if (u >= 6 && u < 27) {
        const int rr = (w * 21) + (u - 6);
        SM[rr * 64 + q32]        = (unsigned short)f2bf(hC[r]);
        SM[2688 + rr * 64 + q32] = (unsigned short)f2bf(wC[r]);
      }
    }
  }
  __syncthreads();

  // ---- W bias preload (8 f32 regs); j>=14 slots become -1e30 masks ----
  const int qw = q32 & 7;
  float wreg[8];
#pragma unroll
  for (int t = 0; t < 8; ++t) {
    const int jt = (t < 4 ? t : t + 4) + 4 * hi;
    if (jt < 14)
      wreg[t] = bfu2f(SM[2688 + (w * 21 + 7 - qw + jt) * 64 + q32]);
    else
      wreg[t] = -1e30f;
  }

  // ---- H bias LDS read base (this wave's nt only) ----
  const int qh0 = q32 >> 3;
  const unsigned short* Hp = SM + ((w ? 24 : 7) - qh0) * 64 + q32;

  // ---- main loop: all 7 chunks, one q-half ----
  const int jj = q32 & 15, ir = q32 >> 4;
  const int xx = bj * 8 + jj - 3;
  const bool jok = (jj < 14) && ((unsigned)xx < 64u);
  const unsigned short* kb = kbuf + ((size_t)((b << 3) + head) * 4096 + xx) * 16 + 8 * hi;
  const int yy0 = bi * 8 + ir - 3;
  const unsigned short* vb = vpln + (size_t)(((b << 3) + head) * 32 + q32) * 5040
                             + (bi * 8) * 72 + bj * 8 + 8 * hi;

  f32x16 acc = {};
  float lrow = 0.f;

  KU k4; k4.u = make_uint4(0, 0, 0, 0);
  if (jok && (unsigned)yy0 < 64u) k4.u = *(const uint4*)(kb + (size_t)yy0 * 1024);
  bf16x8 v0n = *(const bf16x8*)(vb);
  bf16x8 v1n = *(const bf16x8*)(vb + 72);

  for (int c = 0; c < 7; ++c) {
    const bf16x8 kf = k4.v;
    const bf16x8 vf0 = v0n, vf1 = v1n;
    if (c < 6) {
      const int yy = yy0 + 2 * (c + 1);
      KU kn; kn.u = make_uint4(0, 0, 0, 0);
      if (jok && (unsigned)yy < 64u) kn.u = *(const uint4*)(kb + (size_t)yy * 1024);
      k4 = kn;
      v0n = *(const bf16x8*)(vb + (2 * c + 2) * 72);
      v1n = *(const bf16x8*)(vb + (2 * c + 3) * 72);
    }
    __builtin_amdgcn_s_setprio(1);
    f32x16 Cs = __builtin_amdgcn_mfma_f32_32x32x16_bf16(kf, qfrag, z16, 0, 0, 0);
    __builtin_amdgcn_s_setprio(0);
    const float hA = bfu2f(Hp[(2 * c) * 64]);
    const float hB = bfu2f(Hp[(2 * c + 1) * 64]);
    float p[16];
#pragma unroll
    for (int r = 0; r < 16; ++r) {
      const float wv = wreg[(r & 3) + 4 * ((r >> 2) & 1)];
      const float h = (r < 8) ? hA : hB;
      p[r] = exp2f(fmaf(Cs[r], qs, h + wv));
    }
    {
      float s0 = (p[0] + p[1]) + (p[2] + p[3]);
      float s1 = (p[4] + p[5]) + (p[6] + p[7]);
      float s2 = (p[8] + p[9]) + (p[10] + p[11]);
      float s3 = (p[12] + p[13]) + (p[14] + p[15]);
      lrow += (s0 + s1) + (s2 + s3);
    }
    unsigned dw[8], xw[8];
#pragma unroll
    for (int k = 0; k < 8; ++k) dw[k] = cvtpk(p[2 * k], p[2 * k + 1]);
#pragma unroll
    for (int k = 0; k < 8; ++k)
      xw[k] = (unsigned)__builtin_amdgcn_ds_bpermute(swapA, (int)dw[k]);
    FragU8 f0, f1;
    f0.d[0] = hi ? xw[2] : dw[0];
    f0.d[1] = hi ? xw[3] : dw[1];
    f0.d[2] = hi ? dw[2] : xw[0];
    f0.d[3] = hi ? dw[3] : xw[1];
    f1.d[0] = hi ? xw[6] : dw[4];
    f1.d[1] = hi ? xw[7] : dw[5];
    f1.d[2] = hi ? dw[6] : xw[4];
    f1.d[3] = hi ? dw[7] : xw[5];
    __builtin_amdgcn_s_setprio(1);
    acc = __builtin_amdgcn_mfma_f32_32x32x16_bf16(vf0, f0.v, acc, 0, 0, 0);
    acc = __builtin_amdgcn_mfma_f32_32x32x16_bf16(vf1, f1.v, acc, 0, 0, 0);
    __builtin_amdgcn_s_setprio(0);
  }

  // ---- epilogue: no cross-wave merge needed ----
  const float L = lrow + __shfl_xor(lrow, 32);
  const float invL = 1.f / L;
  const int qt = (w << 5) + q32;
  const int yq = bi * 8 + (qt >> 3);
  const int xq = bj * 8 + (q32 & 7);
  float* obase = out + ((size_t)(b * 256 + head * 32) * 4096) + yq * 64 + xq;
#pragma unroll
  for (int r = 0; r < 16; ++r) {
    const int d = (r & 3) + 8 * (r >> 2) + 4 * hi;
    obase[(size_t)d * 4096] = acc[r] * invL;
  }
}

extern "C" void kernel_launch(void* const* d_in, const int* in_sizes, int n_in,
                              void* d_out, int out_size, void* d_ws, size_t ws_size,
                              hipStream_t stream) {
  const float* x          = (const float*)d_in[0];
  const float* q_w        = (const float*)d_in[1];
  const float* kv_w       = (const float*)d_in[2];
  const float* height_rel = (const float*)d_in[3];
  const float* width_rel  = (const float*)d_in[4];
  float* out = (float*)d_out;

  unsigned short* q_bf = (unsigned short*)d_ws;            // 4,194,304 u16
  unsigned short* xT   = q_bf + (size_t)4194304;           // 8,388,608 u16
  unsigned short* w_bf = xT + (size_t)8388608;             //   131,072 u16
  unsigned short* kbuf = w_bf + (size_t)131072;            // 4,194,304 u16
  unsigned short* vpln = kbuf + (size_t)4194304;           // 10,321,920 u16

  haloattn_cvt<<<dim3(64, 4, 8), 256, 0, stream>>>(x, q_w, kv_w, xT, w_bf, vpln);
  haloattn_proj_mfma<<<dim3(32, 2, 8), 512, 0, stream>>>(xT, w_bf, q_bf, kbuf, vpln);
  haloattn_attn_direct<<<4096, 128, 0, stream>>>(q_bf, kbuf, vpln,
                                                 height_rel, width_rel, out);
}

// Round 19
// 66.274 us; speedup vs baseline: 1.1870x; 1.0003x over previous
//
#include <hip/hip_runtime.h>
#include <hip/hip_bf16.h>

#define LOG2E 1.4426950408889634f

typedef __attribute__((ext_vector_type(8))) short bf16x8;
typedef __attribute__((ext_vector_type(4))) float f32x4;
typedef __attribute__((ext_vector_type(16))) float f32x16;

__device__ __forceinline__ short f2bf(float a) {
  __hip_bfloat16 h = __float2bfloat16(a);
  return *reinterpret_cast<short*>(&h);
}
__device__ __forceinline__ unsigned pkbf(float a, float b) {
  return (unsigned)(unsigned short)f2bf(a) | ((unsigned)(unsigned short)f2bf(b) << 16);
}
__device__ __forceinline__ unsigned cvtpk(float a, float b) {
  unsigned r;
  asm("v_cvt_pk_bf16_f32 %0, %1, %2" : "=v"(r) : "v"(a), "v"(b));
  return r;
}
__device__ __forceinline__ float bfu2f(unsigned u16v) {
  unsigned v = u16v << 16; float f; __builtin_memcpy(&f, &v, 4); return f;
}
union FragU8 { unsigned d[4]; bf16x8 v; };
union KU { uint4 u; bf16x8 v; };

// ---------------- Kernel 0: transpose-convert + W convert + V-border zero ----
__global__ __launch_bounds__(256) void haloattn_cvt(
    const float* __restrict__ x, const float* __restrict__ q_w,
    const float* __restrict__ kv_w, unsigned short* __restrict__ xT,
    unsigned short* __restrict__ w_bf, unsigned short* __restrict__ vpln)
{
  __shared__ float Ld[64][68];
  const int t = threadIdx.x;
  const int pt = blockIdx.x, kt = blockIdx.y, b = blockIdx.z;
  const int flat = ((b << 2) + kt) * 64 + pt;   // 0..2047, unique per block
  {
    const int idx = flat * 64 + (t & 63);
    if (t < 64) {
      const float wv = (idx < 32768) ? q_w[idx] : kv_w[idx - 32768];
      w_bf[idx] = (unsigned short)f2bf(wv);
    }
  }
  {
    unsigned short* pl = vpln + (size_t)flat * 5040;
    for (int e = t; e < 944; e += 256) {
      int off;
      if (e < 216) {
        off = e;
      } else if (e < 432) {
        off = 4824 + (e - 216);
      } else {
        const int tt = e - 432;
        const int y = 3 + (tt >> 3);
        const int cidx = tt & 7;
        off = y * 72 + (cidx < 3 ? cidx : cidx + 64);
      }
      pl[off] = 0;
    }
  }
  const float* xb = x + ((size_t)b * 256 + (kt << 6)) * 4096 + (pt << 6);
#pragma unroll
  for (int ps = 0; ps < 4; ++ps) {
    const int kloc = (ps << 4) + (t >> 4);
    const int ploc = (t & 15) << 2;
    float4 v = *(const float4*)(xb + (size_t)kloc * 4096 + ploc);
    *(float4*)&Ld[kloc][ploc] = v;
  }
  __syncthreads();
  const int pl = t >> 2;
  const int ks = (t & 3) << 4;
  float f[16];
#pragma unroll
  for (int i = 0; i < 16; ++i) f[i] = Ld[ks + i][pl];
  uint4 o0, o1;
  o0.x = pkbf(f[0], f[1]);   o0.y = pkbf(f[2], f[3]);
  o0.z = pkbf(f[4], f[5]);   o0.w = pkbf(f[6], f[7]);
  o1.x = pkbf(f[8], f[9]);   o1.y = pkbf(f[10], f[11]);
  o1.z = pkbf(f[12], f[13]); o1.w = pkbf(f[14], f[15]);
  unsigned short* op = xT + ((size_t)(b << 12) + (pt << 6) + pl) * 256 + (kt << 6) + ks;
  *(uint4*)op = o0;
  *(uint4*)(op + 8) = o1;
}

// ---------------- Kernel 1: fused q/kv projection (bf16 MFMA) ----------------
__global__ __launch_bounds__(512, 4) void haloattn_proj_mfma(
    const unsigned short* __restrict__ xT, const unsigned short* __restrict__ w_bf,
    unsigned short* __restrict__ q_bf, unsigned short* __restrict__ kbuf,
    unsigned short* __restrict__ vpln)
{
  __shared__ unsigned short Wt[256][68];
  __shared__ unsigned short Xt[128][68];
  const int tid = threadIdx.x;
  const int w = tid >> 6, l = tid & 63;
  const int b = blockIdx.z, oBase = blockIdx.y << 8, pBase = blockIdx.x << 7;
  const int wm = w >> 1, wn = w & 1;
  const int g = l >> 4, c = l & 15;

  f32x4 acc[4][4] = {};

  const int srow = tid >> 3;
  const int se3  = (tid & 7) << 3;

  for (int chk = 0; chk < 4; ++chk) {
    const int k0 = chk << 6;
#pragma unroll
    for (int ps = 0; ps < 4; ++ps) {
      const int row = (ps << 6) + srow;
      uint4 wv = *(const uint4*)(w_bf + (size_t)(oBase + row) * 256 + k0 + se3);
      char* dst = (char*)&Wt[0][0] + row * 136 + (se3 << 1);
      *(uint2*)dst = make_uint2(wv.x, wv.y);
      *(uint2*)(dst + 8) = make_uint2(wv.z, wv.w);
    }
#pragma unroll
    for (int ps = 0; ps < 2; ++ps) {
      const int p = (ps << 6) + srow;
      uint4 xv = *(const uint4*)(xT + ((size_t)(b << 12) + pBase + p) * 256 + k0 + se3);
      char* dst = (char*)&Xt[0][0] + p * 136 + (se3 << 1);
      *(uint2*)dst = make_uint2(xv.x, xv.y);
      *(uint2*)(dst + 8) = make_uint2(xv.z, xv.w);
    }
    __syncthreads();
#pragma unroll
    for (int kk = 0; kk < 2; ++kk) {
      FragU8 bfr[4];
#pragma unroll
      for (int nf = 0; nf < 4; ++nf) {
        const char* src = (const char*)&Xt[0][0]
            + ((wn << 6) + (nf << 4) + c) * 136 + (kk << 6) + (g << 4);
        uint2 lo = *(const uint2*)src, hi2 = *(const uint2*)(src + 8);
        bfr[nf].d[0] = lo.x; bfr[nf].d[1] = lo.y;
        bfr[nf].d[2] = hi2.x; bfr[nf].d[3] = hi2.y;
      }
#pragma unroll
      for (int mf = 0; mf < 4; ++mf) {
        const char* src = (const char*)&Wt[0][0]
            + ((wm << 6) + (mf << 4) + c) * 136 + (kk << 6) + (g << 4);
        uint2 lo = *(const uint2*)src, hi2 = *(const uint2*)(src + 8);
        FragU8 af;
        af.d[0] = lo.x; af.d[1] = lo.y; af.d[2] = hi2.x; af.d[3] = hi2.y;
#pragma unroll
        for (int nf = 0; nf < 4; ++nf)
          acc[mf][nf] = __builtin_amdgcn_mfma_f32_16x16x32_bf16(af.v, bfr[nf].v, acc[mf][nf], 0, 0, 0);
      }
    }
    __syncthreads();
  }
#pragma unroll
  for (int mf = 0; mf < 4; ++mf) {
    const int o = oBase + (wm << 6) + (mf << 4) + (g << 2);
#pragma unroll
    for (int nf = 0; nf < 4; ++nf) {
      const int p = pBase + (wn << 6) + (nf << 4) + c;
      if (o < 128) {
        uint2 pk2 = make_uint2(pkbf(acc[mf][nf][0], acc[mf][nf][1]),
                               pkbf(acc[mf][nf][2], acc[mf][nf][3]));
        const int head = o >> 4;
        const int z = (b << 3) + head;
        const int y = p >> 6, xx = p & 63;
        const int nbb = ((y >> 3) << 3) + (xx >> 3);
        const int qi = ((y & 7) << 3) + (xx & 7);
        *(uint2*)(q_bf + (((size_t)z * 64 + nbb) * 64 + qi) * 16 + (o & 15)) = pk2;
      } else {
        const int ch = o - 128;
        const int head = (ch * 1366) >> 16;      // ch/48
        const int wi = ch - head * 48;
        const int b8h = (b << 3) + head;
        if (wi < 16) {
          uint2 pk2 = make_uint2(pkbf(acc[mf][nf][0], acc[mf][nf][1]),
                                 pkbf(acc[mf][nf][2], acc[mf][nf][3]));
          *(uint2*)(kbuf + ((size_t)b8h * 4096 + p) * 16 + wi) = pk2;
        } else {
          const int d = wi - 16;
          const int y = p >> 6, xx = p & 63;
          unsigned short* vp = vpln + (size_t)(b8h * 32 + d) * 5040
                               + (size_t)(y + 3) * 72 + (xx + 3);
          vp[0]     = (unsigned short)f2bf(acc[mf][nf][0]);
          vp[5040]  = (unsigned short)f2bf(acc[mf][nf][1]);
          vp[10080] = (unsigned short)f2bf(acc[mf][nf][2]);
          vp[15120] = (unsigned short)f2bf(acc[mf][nf][3]);
        }
      }
    }
  }
}

// ---- attn per-chunk body (shared by the unrolled pipeline steps) ----
__device__ __forceinline__ void attn_chunk(
    int c, const bf16x8 kf, const bf16x8 vf0, const bf16x8 vf1,
    const unsigned short* __restrict__ Hp, const float* __restrict__ wreg,
    const bf16x8 qfrag, f32x16& acc, float& lrow, int swapA, int hi, float qs)
{
  const f32x16 z16 = {};
  __builtin_amdgcn_s_setprio(1);
  f32x16 Cs = __builtin_amdgcn_mfma_f32_32x32x16_bf16(kf, qfrag, z16, 0, 0, 0);
  __builtin_amdgcn_s_setprio(0);
  const float hA = bfu2f(Hp[(2 * c) * 64]);
  const float hB = bfu2f(Hp[(2 * c + 1) * 64]);
  float p[16];
#pragma unroll
  for (int r = 0; r < 16; ++r) {
    const float wv = wreg[(r & 3) + 4 * ((r >> 2) & 1)];
    const float h = (r < 8) ? hA : hB;
    p[r] = exp2f(fmaf(Cs[r], qs, h + wv));
  }
  {
    float s0 = (p[0] + p[1]) + (p[2] + p[3]);
    float s1 = (p[4] + p[5]) + (p[6] + p[7]);
    float s2 = (p[8] + p[9]) + (p[10] + p[11]);
    float s3 = (p[12] + p[13]) + (p[14] + p[15]);
    lrow += (s0 + s1) + (s2 + s3);
  }
  unsigned dw[8], xw[8];
#pragma unroll
  for (int k = 0; k < 8; ++k) dw[k] = cvtpk(p[2 * k], p[2 * k + 1]);
#pragma unroll
  for (int k = 0; k < 8; ++k)
    xw[k] = (unsigned)__builtin_amdgcn_ds_bpermute(swapA, (int)dw[k]);
  FragU8 f0, f1;
  f0.d[0] = hi ? xw[2] : dw[0];
  f0.d[1] = hi ? xw[3] : dw[1];
  f0.d[2] = hi ? dw[2] : xw[0];
  f0.d[3] = hi ? dw[3] : xw[1];
  f1.d[0] = hi ? xw[6] : dw[4];
  f1.d[1] = hi ? xw[7] : dw[5];
  f1.d[2] = hi ? dw[6] : xw[4];
  f1.d[3] = hi ? dw[7] : xw[5];
  __builtin_amdgcn_s_setprio(1);
  acc = __builtin_amdgcn_mfma_f32_32x32x16_bf16(vf0, f0.v, acc, 0, 0, 0);
  acc = __builtin_amdgcn_mfma_f32_32x32x16_bf16(vf1, f1.v, acc, 0, 0, 0);
  __builtin_amdgcn_s_setprio(0);
}

// ---------------- Kernel 2: halo attention, q-half waves + depth-2 prefetch ----
__global__ __launch_bounds__(128, 2) void haloattn_attn_direct(
    const unsigned short* __restrict__ q_bf, const unsigned short* __restrict__ kbuf,
    const unsigned short* __restrict__ vpln,
    const float* __restrict__ height_rel, const float* __restrict__ width_rel,
    float* __restrict__ out)
{
  __shared__ __align__(16) unsigned short SM[5376];

  const int tid = threadIdx.x;
  const int w = tid >> 6;          // wave id = nt half
  const int l = tid & 63;
  const int q32 = l & 31, hi = l >> 5;
  const int wg = blockIdx.x;
  const int swz = ((wg & 7) << 9) | (wg >> 3);
  const int z = swz >> 6;
  const int nb = swz & 63;
  const int b = z >> 3, head = z & 7;
  const int bi = nb >> 3, bj = nb & 7;
  const int swapA = (l ^ 32) << 2;
  const f32x16 z16 = {};
  const float qs = 0.25f * LOG2E;

  const unsigned short* qtile = q_bf + ((size_t)z * 64 + nb) * 1024;
  const bf16x8 qfrag = *(const bf16x8*)(qtile + (((w << 5) + q32) << 4) + 8 * hi);

  unsigned short* HRs = SM;
  unsigned short* WRs = SM + 768;
  if (tid < 54) {
    const int u = tid >> 1, d0 = (tid & 1) << 3;
    float4 a = *(const float4*)(height_rel + u * 16 + d0);
    float4 b4 = *(const float4*)(height_rel + u * 16 + d0 + 4);
    uint4 o;
    o.x = cvtpk(a.x * LOG2E, a.y * LOG2E);
    o.y = cvtpk(a.z * LOG2E, a.w * LOG2E);
    o.z = cvtpk(b4.x * LOG2E, b4.y * LOG2E);
    o.w = cvtpk(b4.z * LOG2E, b4.w * LOG2E);
    *(uint4*)(HRs + u * 24 + d0) = o;
    a = *(const float4*)(width_rel + u * 16 + d0);
    b4 = *(const float4*)(width_rel + u * 16 + d0 + 4);
    o.x = cvtpk(a.x * LOG2E, a.y * LOG2E);
    o.y = cvtpk(a.z * LOG2E, a.w * LOG2E);
    o.z = cvtpk(b4.x * LOG2E, b4.y * LOG2E);
    o.w = cvtpk(b4.z * LOG2E, b4.w * LOG2E);
    *(uint4*)(WRs + u * 24 + d0) = o;
  } else if (tid < 64) {
    const int t = tid - 54;
    const int u = 27 + (t >> 1), d0 = (t & 1) << 3;
    uint4 o = {};
    *(uint4*)(HRs + u * 24 + d0) = o;
    *(uint4*)(WRs + u * 24 + d0) = o;
  }
  __syncthreads();

  {
    bf16x8 hfr = *(const bf16x8*)((const char*)HRs + q32 * 48 + 16 * hi);
    bf16x8 wfr = *(const bf16x8*)((const char*)WRs + q32 * 48 + 16 * hi);
    f32x16 hC = __builtin_amdgcn_mfma_f32_32x32x16_bf16(hfr, qfrag, z16, 0, 0, 0);
    f32x16 wC = __builtin_amdgcn_mfma_f32_32x32x16_bf16(wfr, qfrag, z16, 0, 0, 0);
    __syncthreads();
#pragma unroll
    for (int r = 0; r < 16; ++r) {
      const int u = (r & 3) + 8 * (r >> 2) + 4 * hi;
      if (u >= 6 && u < 27) {
        const int rr = (w * 21) + (u - 6);
        SM[rr * 64 + q32]        = (unsigned short)f2bf(hC[r]);
        SM[2688 + rr * 64 + q32] = (unsigned short)f2bf(wC[r]);
      }
    }
  }
  __syncthreads();

  const int qw = q32 & 7;
  float wreg[8];
#pragma unroll
  for (int t = 0; t < 8; ++t) {
    const int jt = (t < 4 ? t : t + 4) + 4 * hi;
    if (jt < 14)
      wreg[t] = bfu2f(SM[2688 + (w * 21 + 7 - qw + jt) * 64 + q32]);
    else
      wreg[t] = -1e30f;
  }

  const int qh0 = q32 >> 3;
  const unsigned short* Hp = SM + ((w ? 24 : 7) - qh0) * 64 + q32;

  const int jj = q32 & 15, ir = q32 >> 4;
  const int xx = bj * 8 + jj - 3;
  const bool jok = (jj < 14) && ((unsigned)xx < 64u);
  const unsigned short* kb = kbuf + ((size_t)((b << 3) + head) * 4096 + xx) * 16 + 8 * hi;
  const int yy0 = bi * 8 + ir - 3;
  const unsigned short* vb = vpln + (size_t)(((b << 3) + head) * 32 + q32) * 5040
                             + (bi * 8) * 72 + bj * 8 + 8 * hi;

  f32x16 acc = {};
  float lrow = 0.f;

  // ---- depth-2 pipeline: buffers A (even chunks) / B (odd chunks) ----
#define LK(cc, dst) { dst.u = make_uint4(0,0,0,0); const int yy = yy0 + 2*(cc); \
    if (jok && (unsigned)yy < 64u) dst.u = *(const uint4*)(kb + (size_t)yy * 1024); }
#define LV(cc, d0, d1) { d0 = *(const bf16x8*)(vb + (2*(cc)) * 72); \
    d1 = *(const bf16x8*)(vb + (2*(cc)+1) * 72); }

  KU kA, kB;
  bf16x8 vA0, vA1, vB0, vB1;
  LK(0, kA); LV(0, vA0, vA1);
  LK(1, kB); LV(1, vB0, vB1);

  // c=0 (use A, prefetch 2 -> A)
  { KU kn; bf16x8 n0, n1; LK(2, kn); LV(2, n0, n1);
    attn_chunk(0, kA.v, vA0, vA1, Hp, wreg, qfrag, acc, lrow, swapA, hi, qs);
    kA = kn; vA0 = n0; vA1 = n1; }
  // c=1 (use B, prefetch 3 -> B)
  { KU kn; bf16x8 n0, n1; LK(3, kn); LV(3, n0, n1);
    attn_chunk(1, kB.v, vB0, vB1, Hp, wreg, qfrag, acc, lrow, swapA, hi, qs);
    kB = kn; vB0 = n0; vB1 = n1; }
  // c=2 (use A, prefetch 4 -> A)
  { KU kn; bf16x8 n0, n1; LK(4, kn); LV(4, n0, n1);
    attn_chunk(2, kA.v, vA0, vA1, Hp, wreg, qfrag, acc, lrow, swapA, hi, qs);
    kA = kn; vA0 = n0; vA1 = n1; }
  // c=3 (use B, prefetch 5 -> B)
  { KU kn; bf16x8 n0, n1; LK(5, kn); LV(5, n0, n1);
    attn_chunk(3, kB.v, vB0, vB1, Hp, wreg, qfrag, acc, lrow, swapA, hi, qs);
    kB = kn; vB0 = n0; vB1 = n1; }
  // c=4 (use A, prefetch 6 -> A)
  { KU kn; bf16x8 n0, n1; LK(6, kn); LV(6, n0, n1);
    attn_chunk(4, kA.v, vA0, vA1, Hp, wreg, qfrag, acc, lrow, swapA, hi, qs);
    kA = kn; vA0 = n0; vA1 = n1; }
  // c=5 (use B)
  attn_chunk(5, kB.v, vB0, vB1, Hp, wreg, qfrag, acc, lrow, swapA, hi, qs);
  // c=6 (use A)
  attn_chunk(6, kA.v, vA0, vA1, Hp, wreg, qfrag, acc, lrow, swapA, hi, qs);

#undef LK
#undef LV

  // ---- epilogue: no cross-wave merge needed ----
  const float L = lrow + __shfl_xor(lrow, 32);
  const float invL = 1.f / L;
  const int qt = (w << 5) + q32;
  const int yq = bi * 8 + (qt >> 3);
  const int xq = bj * 8 + (q32 & 7);
  float* obase = out + ((size_t)(b * 256 + head * 32) * 4096) + yq * 64 + xq;
#pragma unroll
  for (int r = 0; r < 16; ++r) {
    const int d = (r & 3) + 8 * (r >> 2) + 4 * hi;
    obase[(size_t)d * 4096] = acc[r] * invL;
  }
}

extern "C" void kernel_launch(void* const* d_in, const int* in_sizes, int n_in,
                              void* d_out, int out_size, void* d_ws, size_t ws_size,
                              hipStream_t stream) {
  const float* x          = (const float*)d_in[0];
  const float* q_w        = (const float*)d_in[1];
  const float* kv_w       = (const float*)d_in[2];
  const float* height_rel = (const float*)d_in[3];
  const float* width_rel  = (const float*)d_in[4];
  float* out = (float*)d_out;

  unsigned short* q_bf = (unsigned short*)d_ws;            // 4,194,304 u16
  unsigned short* xT   = q_bf + (size_t)4194304;           // 8,388,608 u16
  unsigned short* w_bf = xT + (size_t)8388608;             //   131,072 u16
  unsigned short* kbuf = w_bf + (size_t)131072;            // 4,194,304 u16
  unsigned short* vpln = kbuf + (size_t)4194304;           // 10,321,920 u16

  haloattn_cvt<<<dim3(64, 4, 8), 256, 0, stream>>>(x, q_w, kv_w, xT, w_bf, vpln);
  haloattn_proj_mfma<<<dim3(32, 2, 8), 512, 0, stream>>>(xT, w_bf, q_bf, kbuf, vpln);
  haloattn_attn_direct<<<4096, 128, 0, stream>>>(q_bf, kbuf, vpln,
                                                 height_rel, width_rel, out);
}

// Round 20
// 64.905 us; speedup vs baseline: 1.2120x; 1.0211x over previous
//
#include <hip/hip_runtime.h>
#include <hip/hip_bf16.h>

#define LOG2E 1.4426950408889634f

typedef __attribute__((ext_vector_type(8))) short bf16x8;
typedef __attribute__((ext_vector_type(4))) float f32x4;
typedef __attribute__((ext_vector_type(16))) float f32x16;

__device__ __forceinline__ short f2bf(float a) {
  __hip_bfloat16 h = __float2bfloat16(a);
  return *reinterpret_cast<short*>(&h);
}
__device__ __forceinline__ unsigned pkbf(float a, float b) {
  return (unsigned)(unsigned short)f2bf(a) | ((unsigned)(unsigned short)f2bf(b) << 16);
}
__device__ __forceinline__ unsigned cvtpk(float a, float b) {
  unsigned r;
  asm("v_cvt_pk_bf16_f32 %0, %1, %2" : "=v"(r) : "v"(a), "v"(b));
  return r;
}
__device__ __forceinline__ float bfu2f(unsigned u16v) {
  unsigned v = u16v << 16; float f; __builtin_memcpy(&f, &v, 4); return f;
}
union FragU8 { unsigned d[4]; bf16x8 v; };
union KU { uint4 u; bf16x8 v; };

// ---------------- Kernel 0: transpose-convert + W convert + V-border zero ----
__global__ __launch_bounds__(256) void haloattn_cvt(
    const float* __restrict__ x, const float* __restrict__ q_w,
    const float* __restrict__ kv_w, unsigned short* __restrict__ xT,
    unsigned short* __restrict__ w_bf, unsigned short* __restrict__ vpln)
{
  __shared__ float Ld[64][68];
  const int t = threadIdx.x;
  const int pt = blockIdx.x, kt = blockIdx.y, b = blockIdx.z;
  const int flat = ((b << 2) + kt) * 64 + pt;   // 0..2047, unique per block
  {
    const int idx = flat * 64 + (t & 63);
    if (t < 64) {
      const float wv = (idx < 32768) ? q_w[idx] : kv_w[idx - 32768];
      w_bf[idx] = (unsigned short)f2bf(wv);
    }
  }
  {
    unsigned short* pl = vpln + (size_t)flat * 5040;
    for (int e = t; e < 944; e += 256) {
      int off;
      if (e < 216) {
        off = e;
      } else if (e < 432) {
        off = 4824 + (e - 216);
      } else {
        const int tt = e - 432;
        const int y = 3 + (tt >> 3);
        const int cidx = tt & 7;
        off = y * 72 + (cidx < 3 ? cidx : cidx + 64);
      }
      pl[off] = 0;
    }
  }
  const float* xb = x + ((size_t)b * 256 + (kt << 6)) * 4096 + (pt << 6);
#pragma unroll
  for (int ps = 0; ps < 4; ++ps) {
    const int kloc = (ps << 4) + (t >> 4);
    const int ploc = (t & 15) << 2;
    float4 v = *(const float4*)(xb + (size_t)kloc * 4096 + ploc);
    *(float4*)&Ld[kloc][ploc] = v;
  }
  __syncthreads();
  const int pl = t >> 2;
  const int ks = (t & 3) << 4;
  float f[16];
#pragma unroll
  for (int i = 0; i < 16; ++i) f[i] = Ld[ks + i][pl];
  uint4 o0, o1;
  o0.x = pkbf(f[0], f[1]);   o0.y = pkbf(f[2], f[3]);
  o0.z = pkbf(f[4], f[5]);   o0.w = pkbf(f[6], f[7]);
  o1.x = pkbf(f[8], f[9]);   o1.y = pkbf(f[10], f[11]);
  o1.z = pkbf(f[12], f[13]); o1.w = pkbf(f[14], f[15]);
  unsigned short* op = xT + ((size_t)(b << 12) + (pt << 6) + pl) * 256 + (kt << 6) + ks;
  *(uint4*)op = o0;
  *(uint4*)(op + 8) = o1;
}

// ---------------- Kernel 1: fused q/kv projection (bf16 MFMA) ----------------
__global__ __launch_bounds__(512, 4) void haloattn_proj_mfma(
    const unsigned short* __restrict__ xT, const unsigned short* __restrict__ w_bf,
    unsigned short* __restrict__ q_bf, unsigned short* __restrict__ kbuf,
    unsigned short* __restrict__ vpln)
{
  __shared__ unsigned short Wt[256][68];
  __shared__ unsigned short Xt[128][68];
  const int tid = threadIdx.x;
  const int w = tid >> 6, l = tid & 63;
  const int b = blockIdx.z, oBase = blockIdx.y << 8, pBase = blockIdx.x << 7;
  const int wm = w >> 1, wn = w & 1;
  const int g = l >> 4, c = l & 15;

  f32x4 acc[4][4] = {};

  const int srow = tid >> 3;
  const int se3  = (tid & 7) << 3;

  for (int chk = 0; chk < 4; ++chk) {
    const int k0 = chk << 6;
#pragma unroll
    for (int ps = 0; ps < 4; ++ps) {
      const int row = (ps << 6) + srow;
      uint4 wv = *(const uint4*)(w_bf + (size_t)(oBase + row) * 256 + k0 + se3);
      char* dst = (char*)&Wt[0][0] + row * 136 + (se3 << 1);
      *(uint2*)dst = make_uint2(wv.x, wv.y);
      *(uint2*)(dst + 8) = make_uint2(wv.z, wv.w);
    }
#pragma unroll
    for (int ps = 0; ps < 2; ++ps) {
      const int p = (ps << 6) + srow;
      uint4 xv = *(const uint4*)(xT + ((size_t)(b << 12) + pBase + p) * 256 + k0 + se3);
      char* dst = (char*)&Xt[0][0] + p * 136 + (se3 << 1);
      *(uint2*)dst = make_uint2(xv.x, xv.y);
      *(uint2*)(dst + 8) = make_uint2(xv.z, xv.w);
    }
    __syncthreads();
#pragma unroll
    for (int kk = 0; kk < 2; ++kk) {
      FragU8 bfr[4];
#pragma unroll
      for (int nf = 0; nf < 4; ++nf) {
        const char* src = (const char*)&Xt[0][0]
            + ((wn << 6) + (nf << 4) + c) * 136 + (kk << 6) + (g << 4);
        uint2 lo = *(const uint2*)src, hi2 = *(const uint2*)(src + 8);
        bfr[nf].d[0] = lo.x; bfr[nf].d[1] = lo.y;
        bfr[nf].d[2] = hi2.x; bfr[nf].d[3] = hi2.y;
      }
#pragma unroll
      for (int mf = 0; mf < 4; ++mf) {
        const char* src = (const char*)&Wt[0][0]
            + ((wm << 6) + (mf << 4) + c) * 136 + (kk << 6) + (g << 4);
        uint2 lo = *(const uint2*)src, hi2 = *(const uint2*)(src + 8);
        FragU8 af;
        af.d[0] = lo.x; af.d[1] = lo.y; af.d[2] = hi2.x; af.d[3] = hi2.y;
#pragma unroll
        for (int nf = 0; nf < 4; ++nf)
          acc[mf][nf] = __builtin_amdgcn_mfma_f32_16x16x32_bf16(af.v, bfr[nf].v, acc[mf][nf], 0, 0, 0);
      }
    }
    __syncthreads();
  }
#pragma unroll
  for (int mf = 0; mf < 4; ++mf) {
    const int o = oBase + (wm << 6) + (mf << 4) + (g << 2);
#pragma unroll
    for (int nf = 0; nf < 4; ++nf) {
      const int p = pBase + (wn << 6) + (nf << 4) + c;
      if (o < 128) {
        uint2 pk2 = make_uint2(pkbf(acc[mf][nf][0], acc[mf][nf][1]),
                               pkbf(acc[mf][nf][2], acc[mf][nf][3]));
        const int head = o >> 4;
        const int z = (b << 3) + head;
        const int y = p >> 6, xx = p & 63;
        const int nbb = ((y >> 3) << 3) + (xx >> 3);
        const int qi = ((y & 7) << 3) + (xx & 7);
        *(uint2*)(q_bf + (((size_t)z * 64 + nbb) * 64 + qi) * 16 + (o & 15)) = pk2;
      } else {
        const int ch = o - 128;
        const int head = (ch * 1366) >> 16;      // ch/48
        const int wi = ch - head * 48;
        const int b8h = (b << 3) + head;
        if (wi < 16) {
          uint2 pk2 = make_uint2(pkbf(acc[mf][nf][0], acc[mf][nf][1]),
                                 pkbf(acc[mf][nf][2], acc[mf][nf][3]));
          *(uint2*)(kbuf + ((size_t)b8h * 4096 + p) * 16 + wi) = pk2;
        } else {
          const int d = wi - 16;
          const int y = p >> 6, xx = p & 63;
          unsigned short* vp = vpln + (size_t)(b8h * 32 + d) * 5040
                               + (size_t)(y + 3) * 72 + (xx + 3);
          vp[0]     = (unsigned short)f2bf(acc[mf][nf][0]);
          vp[5040]  = (unsigned short)f2bf(acc[mf][nf][1]);
          vp[10080] = (unsigned short)f2bf(acc[mf][nf][2]);
          vp[15120] = (unsigned short)f2bf(acc[mf][nf][3]);
        }
      }
    }
  }
}

// ---- attn per-chunk body: repack via v_permlane32_swap_b32 (VALU) ----
// swap(a,b): a' = {lo: a_lo, hi: b_lo-from-(lane-32)}, b' = {lo: a_hi-from-(lane+32), hi: b_hi}
// -> swap(dw0,dw2) yields f0.d[0]=a', f0.d[2]=b' exactly (r19 cndmask table).
__device__ __forceinline__ void attn_chunk(
    int c, const bf16x8 kf, const bf16x8 vf0, const bf16x8 vf1,
    const unsigned short* __restrict__ Hp, const float* __restrict__ wreg,
    const bf16x8 qfrag, f32x16& acc, float& lrow, int hi, float qs)
{
  const f32x16 z16 = {};
  __builtin_amdgcn_s_setprio(1);
  f32x16 Cs = __builtin_amdgcn_mfma_f32_32x32x16_bf16(kf, qfrag, z16, 0, 0, 0);
  __builtin_amdgcn_s_setprio(0);
  const float hA = bfu2f(Hp[(2 * c) * 64]);
  const float hB = bfu2f(Hp[(2 * c + 1) * 64]);
  float p[16];
#pragma unroll
  for (int r = 0; r < 16; ++r) {
    const float wv = wreg[(r & 3) + 4 * ((r >> 2) & 1)];
    const float h = (r < 8) ? hA : hB;
    p[r] = exp2f(fmaf(Cs[r], qs, h + wv));
  }
  {
    float s0 = (p[0] + p[1]) + (p[2] + p[3]);
    float s1 = (p[4] + p[5]) + (p[6] + p[7]);
    float s2 = (p[8] + p[9]) + (p[10] + p[11]);
    float s3 = (p[12] + p[13]) + (p[14] + p[15]);
    lrow += (s0 + s1) + (s2 + s3);
  }
  unsigned dw[8];
#pragma unroll
  for (int k = 0; k < 8; ++k) dw[k] = cvtpk(p[2 * k], p[2 * k + 1]);
  unsigned a0 = dw[0], b0 = dw[2];
  unsigned a1 = dw[1], b1 = dw[3];
  unsigned a2 = dw[4], b2 = dw[6];
  unsigned a3 = dw[5], b3 = dw[7];
  asm("v_permlane32_swap_b32 %0, %1" : "+v"(a0), "+v"(b0));
  asm("v_permlane32_swap_b32 %0, %1" : "+v"(a1), "+v"(b1));
  asm("v_permlane32_swap_b32 %0, %1" : "+v"(a2), "+v"(b2));
  asm("v_permlane32_swap_b32 %0, %1" : "+v"(a3), "+v"(b3));
  FragU8 f0, f1;
  f0.d[0] = a0; f0.d[1] = a1; f0.d[2] = b0; f0.d[3] = b1;
  f1.d[0] = a2; f1.d[1] = a3; f1.d[2] = b2; f1.d[3] = b3;
  __builtin_amdgcn_s_setprio(1);
  acc = __builtin_amdgcn_mfma_f32_32x32x16_bf16(vf0, f0.v, acc, 0, 0, 0);
  acc = __builtin_amdgcn_mfma_f32_32x32x16_bf16(vf1, f1.v, acc, 0, 0, 0);
  __builtin_amdgcn_s_setprio(0);
}

// ---------------- Kernel 2: halo attention, q-half waves + depth-2 prefetch ----
__global__ __launch_bounds__(128, 2) void haloattn_attn_direct(
    const unsigned short* __restrict__ q_bf, const unsigned short* __restrict__ kbuf,
    const unsigned short* __restrict__ vpln,
    const float* __restrict__ height_rel, const float* __restrict__ width_rel,
    float* __restrict__ out)
{
  __shared__ __align__(16) unsigned short SM[5376];

  const int tid = threadIdx.x;
  const int w = tid >> 6;          // wave id = nt half
  const int l = tid & 63;
  const int q32 = l & 31, hi = l >> 5;
  const int wg = blockIdx.x;
  const int swz = ((wg & 7) << 9) | (wg >> 3);
  const int z = swz >> 6;
  const int nb = swz & 63;
  const int b = z >> 3, head = z & 7;
  const int bi = nb >> 3, bj = nb & 7;
  const f32x16 z16 = {};
  const float qs = 0.25f * LOG2E;

  const unsigned short* qtile = q_bf + ((size_t)z * 64 + nb) * 1024;
  const bf16x8 qfrag = *(const bf16x8*)(qtile + (((w << 5) + q32) << 4) + 8 * hi);

  unsigned short* HRs = SM;
  unsigned short* WRs = SM + 768;
  if (tid < 54) {
    const int u = tid >> 1, d0 = (tid & 1) << 3;
    float4 a = *(const float4*)(height_rel + u * 16 + d0);
    float4 b4 = *(const float4*)(height_rel + u * 16 + d0 + 4);
    uint4 o;
    o.x = cvtpk(a.x * LOG2E, a.y * LOG2E);
    o.y = cvtpk(a.z * LOG2E, a.w * LOG2E);
    o.z = cvtpk(b4.x * LOG2E, b4.y * LOG2E);
    o.w = cvtpk(b4.z * LOG2E, b4.w * LOG2E);
    *(uint4*)(HRs + u * 24 + d0) = o;
    a = *(const float4*)(width_rel + u * 16 + d0);
    b4 = *(const float4*)(width_rel + u * 16 + d0 + 4);
    o.x = cvtpk(a.x * LOG2E, a.y * LOG2E);
    o.y = cvtpk(a.z * LOG2E, a.w * LOG2E);
    o.z = cvtpk(b4.x * LOG2E, b4.y * LOG2E);
    o.w = cvtpk(b4.z * LOG2E, b4.w * LOG2E);
    *(uint4*)(WRs + u * 24 + d0) = o;
  } else if (tid < 64) {
    const int t = tid - 54;
    const int u = 27 + (t >> 1), d0 = (t & 1) << 3;
    uint4 o = {};
    *(uint4*)(HRs + u * 24 + d0) = o;
    *(uint4*)(WRs + u * 24 + d0) = o;
  }
  __syncthreads();

  {
    bf16x8 hfr = *(const bf16x8*)((const char*)HRs + q32 * 48 + 16 * hi);
    bf16x8 wfr = *(const bf16x8*)((const char*)WRs + q32 * 48 + 16 * hi);
    f32x16 hC = __builtin_amdgcn_mfma_f32_32x32x16_bf16(hfr, qfrag, z16, 0, 0, 0);
    f32x16 wC = __builtin_amdgcn_mfma_f32_32x32x16_bf16(wfr, qfrag, z16, 0, 0, 0);
    __syncthreads();
#pragma unroll
    for (int r = 0; r < 16; ++r) {
      const int u = (r & 3) + 8 * (r >> 2) + 4 * hi;
      if (u >= 6 && u < 27) {
        const int rr = (w * 21) + (u - 6);
        SM[rr * 64 + q32]        = (unsigned short)f2bf(hC[r]);
        SM[2688 + rr * 64 + q32] = (unsigned short)f2bf(wC[r]);
      }
    }
  }
  __syncthreads();

  const int qw = q32 & 7;
  float wreg[8];
#pragma unroll
  for (int t = 0; t < 8; ++t) {
    const int jt = (t < 4 ? t : t + 4) + 4 * hi;
    if (jt < 14)
      wreg[t] = bfu2f(SM[2688 + (w * 21 + 7 - qw + jt) * 64 + q32]);
    else
      wreg[t] = -1e30f;
  }

  const int qh0 = q32 >> 3;
  const unsigned short* Hp = SM + ((w ? 24 : 7) - qh0) * 64 + q32;

  const int jj = q32 & 15, ir = q32 >> 4;
  const int xx = bj * 8 + jj - 3;
  const bool jok = (jj < 14) && ((unsigned)xx < 64u);
  const unsigned short* kb = kbuf + ((size_t)((b << 3) + head) * 4096 + xx) * 16 + 8 * hi;
  const int yy0 = bi * 8 + ir - 3;
  const unsigned short* vb = vpln + (size_t)(((b << 3) + head) * 32 + q32) * 5040
                             + (bi * 8) * 72 + bj * 8 + 8 * hi;

  f32x16 acc = {};
  float lrow = 0.f;

#define LK(cc, dst) { dst.u = make_uint4(0,0,0,0); const int yy = yy0 + 2*(cc); \
    if (jok && (unsigned)yy < 64u) dst.u = *(const uint4*)(kb + (size_t)yy * 1024); }
#define LV(cc, d0, d1) { d0 = *(const bf16x8*)(vb + (2*(cc)) * 72); \
    d1 = *(const bf16x8*)(vb + (2*(cc)+1) * 72); }

  KU kA, kB;
  bf16x8 vA0, vA1, vB0, vB1;
  LK(0, kA); LV(0, vA0, vA1);
  LK(1, kB); LV(1, vB0, vB1);

  { KU kn; bf16x8 n0, n1; LK(2, kn); LV(2, n0, n1);
    attn_chunk(0, kA.v, vA0, vA1, Hp, wreg, qfrag, acc, lrow, hi, qs);
    kA = kn; vA0 = n0; vA1 = n1; }
  { KU kn; bf16x8 n0, n1; LK(3, kn); LV(3, n0, n1);
    attn_chunk(1, kB.v, vB0, vB1, Hp, wreg, qfrag, acc, lrow, hi, qs);
    kB = kn; vB0 = n0; vB1 = n1; }
  { KU kn; bf16x8 n0, n1; LK(4, kn); LV(4, n0, n1);
    attn_chunk(2, kA.v, vA0, vA1, Hp, wreg, qfrag, acc, lrow, hi, qs);
    kA = kn; vA0 = n0; vA1 = n1; }
  { KU kn; bf16x8 n0, n1; LK(5, kn); LV(5, n0, n1);
    attn_chunk(3, kB.v, vB0, vB1, Hp, wreg, qfrag, acc, lrow, hi, qs);
    kB = kn; vB0 = n0; vB1 = n1; }
  { KU kn; bf16x8 n0, n1; LK(6, kn); LV(6, n0, n1);
    attn_chunk(4, kA.v, vA0, vA1, Hp, wreg, qfrag, acc, lrow, hi, qs);
    kA = kn; vA0 = n0; vA1 = n1; }
  attn_chunk(5, kB.v, vB0, vB1, Hp, wreg, qfrag, acc, lrow, hi, qs);
  attn_chunk(6, kA.v, vA0, vA1, Hp, wreg, qfrag, acc, lrow, hi, qs);

#undef LK
#undef LV

  const float L = lrow + __shfl_xor(lrow, 32);
  const float invL = 1.f / L;
  const int qt = (w << 5) + q32;
  const int yq = bi * 8 + (qt >> 3);
  const int xq = bj * 8 + (q32 & 7);
  float* obase = out + ((size_t)(b * 256 + head * 32) * 4096) + yq * 64 + xq;
#pragma unroll
  for (int r = 0; r < 16; ++r) {
    const int d = (r & 3) + 8 * (r >> 2) + 4 * hi;
    obase[(size_t)d * 4096] = acc[r] * invL;
  }
}

extern "C" void kernel_launch(void* const* d_in, const int* in_sizes, int n_in,
                              void* d_out, int out_size, void* d_ws, size_t ws_size,
                              hipStream_t stream) {
  const float* x          = (const float*)d_in[0];
  const float* q_w        = (const float*)d_in[1];
  const float* kv_w       = (const float*)d_in[2];
  const float* height_rel = (const float*)d_in[3];
  const float* width_rel  = (const float*)d_in[4];
  float* out = (float*)d_out;

  unsigned short* q_bf = (unsigned short*)d_ws;            // 4,194,304 u16
  unsigned short* xT   = q_bf + (size_t)4194304;           // 8,388,608 u16
  unsigned short* w_bf = xT + (size_t)8388608;             //   131,072 u16
  unsigned short* kbuf = w_bf + (size_t)131072;            // 4,194,304 u16
  unsigned short* vpln = kbuf + (size_t)4194304;           // 10,321,920 u16

  haloattn_cvt<<<dim3(64, 4, 8), 256, 0, stream>>>(x, q_w, kv_w, xT, w_bf, vpln);
  haloattn_proj_mfma<<<dim3(32, 2, 8), 512, 0, stream>>>(xT, w_bf, q_bf, kbuf, vpln);
  haloattn_attn_direct<<<4096, 128, 0, stream>>>(q_bf, kbuf, vpln,
                                                 height_rel, width_rel, out);
}

// Round 21
// 64.634 us; speedup vs baseline: 1.2171x; 1.0042x over previous
//
#include <hip/hip_runtime.h>
#include <hip/hip_bf16.h>

#define LOG2E 1.4426950408889634f

typedef __attribute__((ext_vector_type(8))) short bf16x8;
typedef __attribute__((ext_vector_type(4))) float f32x4;
typedef __attribute__((ext_vector_type(16))) float f32x16;

__device__ __forceinline__ short f2bf(float a) {
  __hip_bfloat16 h = __float2bfloat16(a);
  return *reinterpret_cast<short*>(&h);
}
__device__ __forceinline__ unsigned pkbf(float a, float b) {
  return (unsigned)(unsigned short)f2bf(a) | ((unsigned)(unsigned short)f2bf(b) << 16);
}
__device__ __forceinline__ unsigned cvtpk(float a, float b) {
  unsigned r;
  asm("v_cvt_pk_bf16_f32 %0, %1, %2" : "=v"(r) : "v"(a), "v"(b));
  return r;
}
__device__ __forceinline__ float bfu2f(unsigned u16v) {
  unsigned v = u16v << 16; float f; __builtin_memcpy(&f, &v, 4); return f;
}
__device__ __forceinline__ float exthi(unsigned u) {
  unsigned v = u & 0xffff0000u; float f; __builtin_memcpy(&f, &v, 4); return f;
}
union FragU8 { unsigned d[4]; bf16x8 v; };
union KU { uint4 u; bf16x8 v; };

// ---------------- Kernel 0: transpose-convert + W convert + V-border zero ----
__global__ __launch_bounds__(256) void haloattn_cvt(
    const float* __restrict__ x, const float* __restrict__ q_w,
    const float* __restrict__ kv_w, unsigned short* __restrict__ xT,
    unsigned short* __restrict__ w_bf, unsigned short* __restrict__ vpln)
{
  __shared__ float Ld[64][68];
  const int t = threadIdx.x;
  const int pt = blockIdx.x, kt = blockIdx.y, b = blockIdx.z;
  const int flat = ((b << 2) + kt) * 64 + pt;   // 0..2047, unique per block
  {
    const int idx = flat * 64 + (t & 63);
    if (t < 64) {
      const float wv = (idx < 32768) ? q_w[idx] : kv_w[idx - 32768];
      w_bf[idx] = (unsigned short)f2bf(wv);
    }
  }
  {
    unsigned short* pl = vpln + (size_t)flat * 5040;
    for (int e = t; e < 944; e += 256) {
      int off;
      if (e < 216) {
        off = e;
      } else if (e < 432) {
        off = 4824 + (e - 216);
      } else {
        const int tt = e - 432;
        const int y = 3 + (tt >> 3);
        const int cidx = tt & 7;
        off = y * 72 + (cidx < 3 ? cidx : cidx + 64);
      }
      pl[off] = 0;
    }
  }
  const float* xb = x + ((size_t)b * 256 + (kt << 6)) * 4096 + (pt << 6);
#pragma unroll
  for (int ps = 0; ps < 4; ++ps) {
    const int kloc = (ps << 4) + (t >> 4);
    const int ploc = (t & 15) << 2;
    float4 v = *(const float4*)(xb + (size_t)kloc * 4096 + ploc);
    *(float4*)&Ld[kloc][ploc] = v;
  }
  __syncthreads();
  const int pl = t >> 2;
  const int ks = (t & 3) << 4;
  float f[16];
#pragma unroll
  for (int i = 0; i < 16; ++i) f[i] = Ld[ks + i][pl];
  uint4 o0, o1;
  o0.x = pkbf(f[0], f[1]);   o0.y = pkbf(f[2], f[3]);
  o0.z = pkbf(f[4], f[5]);   o0.w = pkbf(f[6], f[7]);
  o1.x = pkbf(f[8], f[9]);   o1.y = pkbf(f[10], f[11]);
  o1.z = pkbf(f[12], f[13]); o1.w = pkbf(f[14], f[15]);
  unsigned short* op = xT + ((size_t)(b << 12) + (pt << 6) + pl) * 256 + (kt << 6) + ks;
  *(uint4*)op = o0;
  *(uint4*)(op + 8) = o1;
}

// ---------------- Kernel 1: fused q/kv projection (bf16 MFMA) ----------------
__global__ __launch_bounds__(512, 4) void haloattn_proj_mfma(
    const unsigned short* __restrict__ xT, const unsigned short* __restrict__ w_bf,
    unsigned short* __restrict__ q_bf, unsigned short* __restrict__ kbuf,
    unsigned short* __restrict__ vpln)
{
  __shared__ unsigned short Wt[256][68];
  __shared__ unsigned short Xt[128][68];
  const int tid = threadIdx.x;
  const int w = tid >> 6, l = tid & 63;
  const int b = blockIdx.z, oBase = blockIdx.y << 8, pBase = blockIdx.x << 7;
  const int wm = w >> 1, wn = w & 1;
  const int g = l >> 4, c = l & 15;

  f32x4 acc[4][4] = {};

  const int srow = tid >> 3;
  const int se3  = (tid & 7) << 3;

  for (int chk = 0; chk < 4; ++chk) {
    const int k0 = chk << 6;
#pragma unroll
    for (int ps = 0; ps < 4; ++ps) {
      const int row = (ps << 6) + srow;
      uint4 wv = *(const uint4*)(w_bf + (size_t)(oBase + row) * 256 + k0 + se3);
      char* dst = (char*)&Wt[0][0] + row * 136 + (se3 << 1);
      *(uint2*)dst = make_uint2(wv.x, wv.y);
      *(uint2*)(dst + 8) = make_uint2(wv.z, wv.w);
    }
#pragma unroll
    for (int ps = 0; ps < 2; ++ps) {
      const int p = (ps << 6) + srow;
      uint4 xv = *(const uint4*)(xT + ((size_t)(b << 12) + pBase + p) * 256 + k0 + se3);
      char* dst = (char*)&Xt[0][0] + p * 136 + (se3 << 1);
      *(uint2*)dst = make_uint2(xv.x, xv.y);
      *(uint2*)(dst + 8) = make_uint2(xv.z, xv.w);
    }
    __syncthreads();
#pragma unroll
    for (int kk = 0; kk < 2; ++kk) {
      FragU8 bfr[4];
#pragma unroll
      for (int nf = 0; nf < 4; ++nf) {
        const char* src = (const char*)&Xt[0][0]
            + ((wn << 6) + (nf << 4) + c) * 136 + (kk << 6) + (g << 4);
        uint2 lo = *(const uint2*)src, hi2 = *(const uint2*)(src + 8);
        bfr[nf].d[0] = lo.x; bfr[nf].d[1] = lo.y;
        bfr[nf].d[2] = hi2.x; bfr[nf].d[3] = hi2.y;
      }
#pragma unroll
      for (int mf = 0; mf < 4; ++mf) {
        const char* src = (const char*)&Wt[0][0]
            + ((wm << 6) + (mf << 4) + c) * 136 + (kk << 6) + (g << 4);
        uint2 lo = *(const uint2*)src, hi2 = *(const uint2*)(src + 8);
        FragU8 af;
        af.d[0] = lo.x; af.d[1] = lo.y; af.d[2] = hi2.x; af.d[3] = hi2.y;
#pragma unroll
        for (int nf = 0; nf < 4; ++nf)
          acc[mf][nf] = __builtin_amdgcn_mfma_f32_16x16x32_bf16(af.v, bfr[nf].v, acc[mf][nf], 0, 0, 0);
      }
    }
    __syncthreads();
  }
#pragma unroll
  for (int mf = 0; mf < 4; ++mf) {
    const int o = oBase + (wm << 6) + (mf << 4) + (g << 2);
#pragma unroll
    for (int nf = 0; nf < 4; ++nf) {
      const int p = pBase + (wn << 6) + (nf << 4) + c;
      if (o < 128) {
        uint2 pk2 = make_uint2(pkbf(acc[mf][nf][0], acc[mf][nf][1]),
                               pkbf(acc[mf][nf][2], acc[mf][nf][3]));
        const int head = o >> 4;
        const int z = (b << 3) + head;
        const int y = p >> 6, xx = p & 63;
        const int nbb = ((y >> 3) << 3) + (xx >> 3);
        const int qi = ((y & 7) << 3) + (xx & 7);
        *(uint2*)(q_bf + (((size_t)z * 64 + nbb) * 64 + qi) * 16 + (o & 15)) = pk2;
      } else {
        const int ch = o - 128;
        const int head = (ch * 1366) >> 16;      // ch/48
        const int wi = ch - head * 48;
        const int b8h = (b << 3) + head;
        if (wi < 16) {
          uint2 pk2 = make_uint2(pkbf(acc[mf][nf][0], acc[mf][nf][1]),
                                 pkbf(acc[mf][nf][2], acc[mf][nf][3]));
          *(uint2*)(kbuf + ((size_t)b8h * 4096 + p) * 16 + wi) = pk2;
        } else {
          const int d = wi - 16;
          const int y = p >> 6, xx = p & 63;
          unsigned short* vp = vpln + (size_t)(b8h * 32 + d) * 5040
                               + (size_t)(y + 3) * 72 + (xx + 3);
          vp[0]     = (unsigned short)f2bf(acc[mf][nf][0]);
          vp[5040]  = (unsigned short)f2bf(acc[mf][nf][1]);
          vp[10080] = (unsigned short)f2bf(acc[mf][nf][2]);
          vp[15120] = (unsigned short)f2bf(acc[mf][nf][3]);
        }
      }
    }
  }
}

// ---- attn per-chunk body: H bias from packed register, repack via permlane ----
__device__ __forceinline__ void attn_chunk(
    unsigned hpkc, const bf16x8 kf, const bf16x8 vf0, const bf16x8 vf1,
    const float* __restrict__ wreg,
    const bf16x8 qfrag, f32x16& acc, float& lrow, int hi, float qs)
{
  const f32x16 z16 = {};
  __builtin_amdgcn_s_setprio(1);
  f32x16 Cs = __builtin_amdgcn_mfma_f32_32x32x16_bf16(kf, qfrag, z16, 0, 0, 0);
  __builtin_amdgcn_s_setprio(0);
  const float hA = bfu2f(hpkc & 0xffffu);
  const float hB = exthi(hpkc);
  float p[16];
#pragma unroll
  for (int r = 0; r < 16; ++r) {
    const float wv = wreg[(r & 3) + 4 * ((r >> 2) & 1)];
    const float h = (r < 8) ? hA : hB;
    p[r] = exp2f(fmaf(Cs[r], qs, h + wv));
  }
  {
    float s0 = (p[0] + p[1]) + (p[2] + p[3]);
    float s1 = (p[4] + p[5]) + (p[6] + p[7]);
    float s2 = (p[8] + p[9]) + (p[10] + p[11]);
    float s3 = (p[12] + p[13]) + (p[14] + p[15]);
    lrow += (s0 + s1) + (s2 + s3);
  }
  unsigned dw[8];
#pragma unroll
  for (int k = 0; k < 8; ++k) dw[k] = cvtpk(p[2 * k], p[2 * k + 1]);
  unsigned a0 = dw[0], b0 = dw[2];
  unsigned a1 = dw[1], b1 = dw[3];
  unsigned a2 = dw[4], b2 = dw[6];
  unsigned a3 = dw[5], b3 = dw[7];
  asm("v_permlane32_swap_b32 %0, %1" : "+v"(a0), "+v"(b0));
  asm("v_permlane32_swap_b32 %0, %1" : "+v"(a1), "+v"(b1));
  asm("v_permlane32_swap_b32 %0, %1" : "+v"(a2), "+v"(b2));
  asm("v_permlane32_swap_b32 %0, %1" : "+v"(a3), "+v"(b3));
  FragU8 f0, f1;
  f0.d[0] = a0; f0.d[1] = a1; f0.d[2] = b0; f0.d[3] = b1;
  f1.d[0] = a2; f1.d[1] = a3; f1.d[2] = b2; f1.d[3] = b3;
  __builtin_amdgcn_s_setprio(1);
  acc = __builtin_amdgcn_mfma_f32_32x32x16_bf16(vf0, f0.v, acc, 0, 0, 0);
  acc = __builtin_amdgcn_mfma_f32_32x32x16_bf16(vf1, f1.v, acc, 0, 0, 0);
  __builtin_amdgcn_s_setprio(0);
}

// ---------------- Kernel 2: halo attention, q-half waves, reg-resident biases ----
__global__ __launch_bounds__(128, 2) void haloattn_attn_direct(
    const unsigned short* __restrict__ q_bf, const unsigned short* __restrict__ kbuf,
    const unsigned short* __restrict__ vpln,
    const float* __restrict__ height_rel, const float* __restrict__ width_rel,
    float* __restrict__ out)
{
  __shared__ __align__(16) unsigned short SM[5376];

  const int tid = threadIdx.x;
  const int w = tid >> 6;          // wave id = nt half
  const int l = tid & 63;
  const int q32 = l & 31, hi = l >> 5;
  const int wg = blockIdx.x;
  const int swz = ((wg & 7) << 9) | (wg >> 3);
  const int z = swz >> 6;
  const int nb = swz & 63;
  const int b = z >> 3, head = z & 7;
  const int bi = nb >> 3, bj = nb & 7;
  const f32x16 z16 = {};
  const float qs = 0.25f * LOG2E;

  const unsigned short* qtile = q_bf + ((size_t)z * 64 + nb) * 1024;
  const bf16x8 qfrag = *(const bf16x8*)(qtile + (((w << 5) + q32) << 4) + 8 * hi);

  unsigned short* HRs = SM;
  unsigned short* WRs = SM + 768;
  if (tid < 54) {
    const int u = tid >> 1, d0 = (tid & 1) << 3;
    float4 a = *(const float4*)(height_rel + u * 16 + d0);
    float4 b4 = *(const float4*)(height_rel + u * 16 + d0 + 4);
    uint4 o;
    o.x = cvtpk(a.x * LOG2E, a.y * LOG2E);
    o.y = cvtpk(a.z * LOG2E, a.w * LOG2E);
    o.z = cvtpk(b4.x * LOG2E, b4.y * LOG2E);
    o.w = cvtpk(b4.z * LOG2E, b4.w * LOG2E);
    *(uint4*)(HRs + u * 24 + d0) = o;
    a = *(const float4*)(width_rel + u * 16 + d0);
    b4 = *(const float4*)(width_rel + u * 16 + d0 + 4);
    o.x = cvtpk(a.x * LOG2E, a.y * LOG2E);
    o.y = cvtpk(a.z * LOG2E, a.w * LOG2E);
    o.z = cvtpk(b4.x * LOG2E, b4.y * LOG2E);
    o.w = cvtpk(b4.z * LOG2E, b4.w * LOG2E);
    *(uint4*)(WRs + u * 24 + d0) = o;
  } else if (tid < 64) {
    const int t = tid - 54;
    const int u = 27 + (t >> 1), d0 = (t & 1) << 3;
    uint4 o = {};
    *(uint4*)(HRs + u * 24 + d0) = o;
    *(uint4*)(WRs + u * 24 + d0) = o;
  }
  __syncthreads();

  {
    bf16x8 hfr = *(const bf16x8*)((const char*)HRs + q32 * 48 + 16 * hi);
    bf16x8 wfr = *(const bf16x8*)((const char*)WRs + q32 * 48 + 16 * hi);
    f32x16 hC = __builtin_amdgcn_mfma_f32_32x32x16_bf16(hfr, qfrag, z16, 0, 0, 0);
    f32x16 wC = __builtin_amdgcn_mfma_f32_32x32x16_bf16(wfr, qfrag, z16, 0, 0, 0);
    __syncthreads();
#pragma unroll
    for (int r = 0; r < 16; ++r) {
      const int u = (r & 3) + 8 * (r >> 2) + 4 * hi;
      if (u >= 6 && u < 27) {
        const int rr = (w * 21) + (u - 6);
        SM[rr * 64 + q32]        = (unsigned short)f2bf(hC[r]);
        SM[2688 + rr * 64 + q32] = (unsigned short)f2bf(wC[r]);
      }
    }
  }
  __syncthreads();

  const int qw = q32 & 7;
  float wreg[8];
#pragma unroll
  for (int t = 0; t < 8; ++t) {
    const int jt = (t < 4 ? t : t + 4) + 4 * hi;
    if (jt < 14)
      wreg[t] = bfu2f(SM[2688 + (w * 21 + 7 - qw + jt) * 64 + q32]);
    else
      wreg[t] = -1e30f;
  }

  // ---- H bias hoist: 14 LDS reads -> 7 packed regs (prologue, off critical path) ----
  const int qh0 = q32 >> 3;
  const unsigned short* Hp = SM + ((w ? 24 : 7) - qh0) * 64 + q32;
  unsigned hpk[7];
#pragma unroll
  for (int c7 = 0; c7 < 7; ++c7) {
    const unsigned lo = Hp[(2 * c7) * 64];
    const unsigned hi2 = Hp[(2 * c7 + 1) * 64];
    hpk[c7] = lo | (hi2 << 16);
  }

  const int jj = q32 & 15, ir = q32 >> 4;
  const int xx = bj * 8 + jj - 3;
  const bool jok = (jj < 14) && ((unsigned)xx < 64u);
  const unsigned short* kb = kbuf + ((size_t)((b << 3) + head) * 4096 + xx) * 16 + 8 * hi;
  const int yy0 = bi * 8 + ir - 3;
  const unsigned short* vb = vpln + (size_t)(((b << 3) + head) * 32 + q32) * 5040
                             + (bi * 8) * 72 + bj * 8 + 8 * hi;

  f32x16 acc = {};
  float lrow = 0.f;

#define LK(cc, dst) { dst.u = make_uint4(0,0,0,0); const int yy = yy0 + 2*(cc); \
    if (jok && (unsigned)yy < 64u) dst.u = *(const uint4*)(kb + (size_t)yy * 1024); }
#define LV(cc, d0, d1) { d0 = *(const bf16x8*)(vb + (2*(cc)) * 72); \
    d1 = *(const bf16x8*)(vb + (2*(cc)+1) * 72); }

  KU kA, kB;
  bf16x8 vA0, vA1, vB0, vB1;
  LK(0, kA); LV(0, vA0, vA1);
  LK(1, kB); LV(1, vB0, vB1);

  { KU kn; bf16x8 n0, n1; LK(2, kn); LV(2, n0, n1);
    attn_chunk(hpk[0], kA.v, vA0, vA1, wreg, qfrag, acc, lrow, hi, qs);
    kA = kn; vA0 = n0; vA1 = n1; }
  { KU kn; bf16x8 n0, n1; LK(3, kn); LV(3, n0, n1);
    attn_chunk(hpk[1], kB.v, vB0, vB1, wreg, qfrag, acc, lrow, hi, qs);
    kB = kn; vB0 = n0; vB1 = n1; }
  { KU kn; bf16x8 n0, n1; LK(4, kn); LV(4, n0, n1);
    attn_chunk(hpk[2], kA.v, vA0, vA1, wreg, qfrag, acc, lrow, hi, qs);
    kA = kn; vA0 = n0; vA1 = n1; }
  { KU kn; bf16x8 n0, n1; LK(5, kn); LV(5, n0, n1);
    attn_chunk(hpk[3], kB.v, vB0, vB1, wreg, qfrag, acc, lrow, hi, qs);
    kB = kn; vB0 = n0; vB1 = n1; }
  { KU kn; bf16x8 n0, n1; LK(6, kn); LV(6, n0, n1);
    attn_chunk(hpk[4], kA.v, vA0, vA1, wreg, qfrag, acc, lrow, hi, qs);
    kA = kn; vA0 = n0; vA1 = n1; }
  attn_chunk(hpk[5], kB.v, vB0, vB1, wreg, qfrag, acc, lrow, hi, qs);
  attn_chunk(hpk[6], kA.v, vA0, vA1, wreg, qfrag, acc, lrow, hi, qs);

#undef LK
#undef LV

  const float L = lrow + __shfl_xor(lrow, 32);
  const float invL = 1.f / L;
  const int qt = (w << 5) + q32;
  const int yq = bi * 8 + (qt >> 3);
  const int xq = bj * 8 + (q32 & 7);
  float* obase = out + ((size_t)(b * 256 + head * 32) * 4096) + yq * 64 + xq;
#pragma unroll
  for (int r = 0; r < 16; ++r) {
    const int d = (r & 3) + 8 * (r >> 2) + 4 * hi;
    obase[(size_t)d * 4096] = acc[r] * invL;
  }
}

extern "C" void kernel_launch(void* const* d_in, const int* in_sizes, int n_in,
                              void* d_out, int out_size, void* d_ws, size_t ws_size,
                              hipStream_t stream) {
  const float* x          = (const float*)d_in[0];
  const float* q_w        = (const float*)d_in[1];
  const float* kv_w       = (const float*)d_in[2];
  const float* height_rel = (const float*)d_in[3];
  const float* width_rel  = (const float*)d_in[4];
  float* out = (float*)d_out;

  unsigned short* q_bf = (unsigned short*)d_ws;            // 4,194,304 u16
  unsigned short* xT   = q_bf + (size_t)4194304;           // 8,388,608 u16
  unsigned short* w_bf = xT + (size_t)8388608;             //   131,072 u16
  unsigned short* kbuf = w_bf + (size_t)131072;            // 4,194,304 u16
  unsigned short* vpln = kbuf + (size_t)4194304;           // 10,321,920 u16

  haloattn_cvt<<<dim3(64, 4, 8), 256, 0, stream>>>(x, q_w, kv_w, xT, w_bf, vpln);
  haloattn_proj_mfma<<<dim3(32, 2, 8), 512, 0, stream>>>(xT, w_bf, q_bf, kbuf, vpln);
  haloattn_attn_direct<<<4096, 128, 0, stream>>>(q_bf, kbuf, vpln,
                                                 height_rel, width_rel, out);
}